// Round 5
// baseline (287.264 us; speedup 1.0000x reference)
//
#include <hip/hip_runtime.h>
#include <stdint.h>

typedef __attribute__((ext_vector_type(8))) short short8;   // 8 bf16 (4 VGPRs)
typedef __attribute__((ext_vector_type(4))) float f32x4;    // MFMA acc

#define MFMA16(a, b, c) __builtin_amdgcn_mfma_f32_16x16x32_bf16((a), (b), (c), 0, 0, 0)

__device__ __forceinline__ float b2f(unsigned short u) {
    union { unsigned u; float f; } c; c.u = ((unsigned)u) << 16; return c.f;
}
__device__ __forceinline__ unsigned short f2b(float f) {
    union { float f; unsigned u; } c; c.f = f;
    unsigned r = c.u + 0x7FFF + ((c.u >> 16) & 1);   // round-to-nearest-even
    return (unsigned short)(r >> 16);
}
__device__ __forceinline__ unsigned f_as_u(float f) {
    union { float f; unsigned u; } c; c.f = f; return c.u;
}
__device__ __forceinline__ float u_as_f(unsigned u) {
    union { unsigned u; float f; } c; c.u = u; return c.f;
}

// async global->LDS, 16B per lane. LDS dest is wave-uniform base + lane*16
// (m104/m108 semantics). flat->local addrspacecast lowers to 32-bit trunc,
// so going through uintptr_t is bit-exact.
__device__ __forceinline__ void g2lds16(const unsigned short* g, unsigned lds_byte_off) {
    __builtin_amdgcn_global_load_lds(
        (const __attribute__((address_space(1))) void*)(uintptr_t)g,
        (__attribute__((address_space(3))) void*)(uintptr_t)lds_byte_off,
        16, 0, 0);
}

// ---------------------------------------------------------------------------
// Dtype canary (proven): flag=1 => f32 inputs, 0 => bf16.
// ---------------------------------------------------------------------------
__global__ void detect_dtype(const unsigned short* __restrict__ x, int* __restrict__ flag) {
    __shared__ int cnt;
    if (threadIdx.x == 0) cnt = 0;
    __syncthreads();
    int insane = 0;
    #pragma unroll
    for (int j = 0; j < 4; ++j) {
        unsigned short u = x[threadIdx.x * 4 + j];
        int e = (u >> 7) & 0xFF;
        if ((e >= 1 && e <= 90) || e >= 165) insane++;
    }
    atomicAdd(&cnt, insane);
    __syncthreads();
    if (threadIdx.x == 0) *flag = (cnt > 128) ? 1 : 0;
}

__global__ __launch_bounds__(256) void convert_bf16(const void* __restrict__ src,
                                                    unsigned short* __restrict__ dst,
                                                    int n, const int* __restrict__ flag) {
    int i = blockIdx.x * 256 + threadIdx.x;
    if (i >= n) return;
    if (*flag) dst[i] = f2b(((const float*)src)[i]);
    else       dst[i] = ((const unsigned short*)src)[i];
}

// all 4 bias vectors in one launch: grid 16 x 256
__global__ __launch_bounds__(256) void convert_bias(const void* __restrict__ s0, const void* __restrict__ s1,
                                                    const void* __restrict__ s2, const void* __restrict__ s3,
                                                    unsigned short* __restrict__ dstB3,
                                                    unsigned short* __restrict__ dstBo,
                                                    const int* __restrict__ flag) {
    const int which = blockIdx.x >> 2;
    const int i = (blockIdx.x & 3) * 256 + threadIdx.x;
    const void* src = (which == 0) ? s0 : (which == 1) ? s1 : (which == 2) ? s2 : s3;
    unsigned short v = (*flag) ? f2b(((const float*)src)[i]) : ((const unsigned short*)src)[i];
    if (which < 3) dstB3[which * 1024 + i] = v;
    else dstBo[i] = v;
}

// ---------------------------------------------------------------------------
// Fused convert + transpose: src [1024][1024] (f32 or bf16) -> dst bf16 [c][r]
// ---------------------------------------------------------------------------
__global__ __launch_bounds__(256) void convtrans_k(const void* __restrict__ src,
                                                   unsigned short* __restrict__ dst,
                                                   const int* __restrict__ flag) {
    __shared__ __align__(16) unsigned short tile[64 * 72];
    const int tid = threadIdx.x;
    const int r0 = blockIdx.y * 64, c0 = blockIdx.x * 64;
    const int rb = tid >> 3, c = (tid & 7) * 8;
    if (*flag) {
        const float* s = (const float*)src;
        #pragma unroll
        for (int it = 0; it < 2; ++it) {
            int rr = it * 32 + rb;
            float4 f0 = *(const float4*)&s[(size_t)(r0 + rr) * 1024 + c0 + c];
            float4 f1 = *(const float4*)&s[(size_t)(r0 + rr) * 1024 + c0 + c + 4];
            unsigned short* t = &tile[rr * 72 + c];
            t[0] = f2b(f0.x); t[1] = f2b(f0.y); t[2] = f2b(f0.z); t[3] = f2b(f0.w);
            t[4] = f2b(f1.x); t[5] = f2b(f1.y); t[6] = f2b(f1.z); t[7] = f2b(f1.w);
        }
    } else {
        const unsigned short* s = (const unsigned short*)src;
        #pragma unroll
        for (int it = 0; it < 2; ++it) {
            int rr = it * 32 + rb;
            *(short8*)&tile[rr * 72 + c] = *(const short8*)&s[(size_t)(r0 + rr) * 1024 + c0 + c];
        }
    }
    __syncthreads();
    #pragma unroll
    for (int it = 0; it < 2; ++it) {
        int n = it * 32 + rb, k8 = c;
        union { short8 s; unsigned short u[8]; } tmp;
        #pragma unroll
        for (int j = 0; j < 8; ++j) tmp.u[j] = tile[(k8 + j) * 72 + n];
        *(short8*)&dst[(size_t)(c0 + n) * 1024 + r0 + k8] = tmp.s;
    }
}

// ---------------------------------------------------------------------------
// V transpose: qkv [4096][3072] (v slice) -> VtG [bh][dk][seq]
// ---------------------------------------------------------------------------
__global__ __launch_bounds__(256) void vtrans(const unsigned short* __restrict__ qkv,
                                              unsigned short* __restrict__ VtG) {
    __shared__ __align__(16) unsigned short tile[64 * 72];
    const int st = blockIdx.x, bh = blockIdx.y;
    const int b = bh >> 4, h = bh & 15;
    const int tid = threadIdx.x;
    const int rb = tid >> 3, c = (tid & 7) * 8;
    #pragma unroll
    for (int it = 0; it < 2; ++it) {
        int r = it * 32 + rb;
        *(short8*)&tile[r * 72 + c] =
            *(const short8*)&qkv[(size_t)(b * 2048 + st * 64 + r) * 3072 + 2048 + h * 64 + c];
    }
    __syncthreads();
    #pragma unroll
    for (int it = 0; it < 2; ++it) {
        int n = it * 32 + rb;
        union { short8 s; unsigned short u[8]; } tmp;
        #pragma unroll
        for (int j = 0; j < 8; ++j) tmp.u[j] = tile[(c + j) * 72 + n];
        *(short8*)&VtG[(size_t)(bh * 64 + n) * 2048 + st * 64 + c] = tmp.s;
    }
}

// ---------------------------------------------------------------------------
// C = relu(A[M,K] @ BT[N,K]^T + bias[N]); m97 structure: global_load_lds
// width-16 staging into unpadded 128x32 LDS, 2-barrier K-loop.
// ---------------------------------------------------------------------------
__global__ __launch_bounds__(256) void gemm_bias_relu(const unsigned short* __restrict__ A,
                                                      const unsigned short* __restrict__ BT,
                                                      const unsigned short* __restrict__ bias,
                                                      void* __restrict__ C,
                                                      const int* __restrict__ flag,
                                                      int M, int N, int K, int out_is_final) {
    __shared__ __align__(16) unsigned short As[128 * 32];   // unpadded: global_load_lds needs contiguity
    __shared__ __align__(16) unsigned short Bs[128 * 32];
    const int tid = threadIdx.x;
    const int wave = tid >> 6, lane = tid & 63;
    const int quad = lane >> 4, l16 = lane & 15;
    const int wm = wave >> 1, wn = wave & 1;
    const int m0 = blockIdx.y * 128, n0 = blockIdx.x * 128;

    f32x4 acc[4][4];
    #pragma unroll
    for (int i = 0; i < 4; i++)
        #pragma unroll
        for (int j = 0; j < 4; j++) acc[i][j] = (f32x4){0.f, 0.f, 0.f, 0.f};

    // staging: wave w covers rows [w*32, w*32+32) via 2 insts of 16 rows (1KB each)
    const int srow = wave * 32 + (lane >> 2);
    const int sc8  = (lane & 3) * 8;
    const unsigned short* gA0 = A  + (size_t)(m0 + srow) * K + sc8;
    const unsigned short* gA1 = gA0 + (size_t)16 * K;
    const unsigned short* gB0 = BT + (size_t)(n0 + srow) * K + sc8;
    const unsigned short* gB1 = gB0 + (size_t)16 * K;
    const unsigned ldsA = (unsigned)(uintptr_t)&As[0] + wave * 2048;
    const unsigned ldsB = (unsigned)(uintptr_t)&Bs[0] + wave * 2048;

    for (int k0 = 0; k0 < K; k0 += 32) {
        __syncthreads();
        g2lds16(gA0 + k0, ldsA);
        g2lds16(gA1 + k0, ldsA + 1024);
        g2lds16(gB0 + k0, ldsB);
        g2lds16(gB1 + k0, ldsB + 1024);
        __syncthreads();
        short8 af[4], bf[4];
        #pragma unroll
        for (int i = 0; i < 4; i++) af[i] = *(const short8*)&As[(wm * 64 + i * 16 + l16) * 32 + quad * 8];
        #pragma unroll
        for (int j = 0; j < 4; j++) bf[j] = *(const short8*)&Bs[(wn * 64 + j * 16 + l16) * 32 + quad * 8];
        #pragma unroll
        for (int i = 0; i < 4; i++)
            #pragma unroll
            for (int j = 0; j < 4; j++)
                acc[i][j] = MFMA16(af[i], bf[j], acc[i][j]);
    }

    const int f32out = out_is_final && (*flag != 0);
    #pragma unroll
    for (int j = 0; j < 4; j++) {
        const int col = n0 + wn * 64 + j * 16 + l16;
        const float bj = b2f(bias[col]);
        #pragma unroll
        for (int i = 0; i < 4; i++) {
            const int rowb = m0 + wm * 64 + i * 16 + quad * 4;
            #pragma unroll
            for (int r = 0; r < 4; r++) {
                float v = acc[i][j][r] + bj;
                v = v > 0.f ? v : 0.f;
                if (f32out) ((float*)C)[(size_t)(rowb + r) * N + col] = v;
                else ((unsigned short*)C)[(size_t)(rowb + r) * N + col] = f2b(v);
            }
        }
    }
}

// ---------------------------------------------------------------------------
// Attention, no-max softmax + deferred row-sum (round-4 proven), now with
// register double-buffered K/V staging and conflict-free P stride (68).
// Block = 128 q-rows of one (b,h); 4 waves x 2 16-row frags. 64-key tiles.
// ---------------------------------------------------------------------------
__global__ __launch_bounds__(256) void attn_kernel(const unsigned short* __restrict__ qkv,
                                                   const unsigned short* __restrict__ VtG,
                                                   const int* __restrict__ mask,
                                                   unsigned short* __restrict__ out) {
    __shared__ __align__(16) unsigned short Ks[64 * 72];    // [key][dk]
    __shared__ __align__(16) unsigned short Vs[64 * 72];    // [dk][key]
    __shared__ __align__(16) unsigned short Ps[4][16 * 68]; // per-wave P; stride 68 => 4 quads hit disjoint banks
    __shared__ int maskS[2048];

    const int qt = blockIdx.x, bh = blockIdx.y;
    const int b = bh >> 4, h = bh & 15;
    const int tid = threadIdx.x, wave = tid >> 6, lane = tid & 63;
    const int quad = lane >> 4, l16 = lane & 15;

    for (int i = tid; i < 2048; i += 256) maskS[i] = mask[b * 2048 + i];

    const int qrowA = qt * 128 + wave * 16 + l16;
    const unsigned short* qpA = qkv + (size_t)(b * 2048 + qrowA) * 3072 + h * 64;
    const unsigned short* qpB = qpA + (size_t)64 * 3072;
    const short8 qa0 = *(const short8*)(qpA + quad * 8);
    const short8 qa1 = *(const short8*)(qpA + 32 + quad * 8);
    const short8 qb0 = *(const short8*)(qpB + quad * 8);
    const short8 qb1 = *(const short8*)(qpB + 32 + quad * 8);

    f32x4 oA[4], oB[4];
    float lA[4], lB[4];
    #pragma unroll
    for (int n = 0; n < 4; n++) { oA[n] = (f32x4){0.f,0.f,0.f,0.f}; oB[n] = (f32x4){0.f,0.f,0.f,0.f}; }
    #pragma unroll
    for (int r = 0; r < 4; r++) { lA[r] = 0.f; lB[r] = 0.f; }

    const int srow = tid >> 2;          // 0..63
    const int scol = (tid & 3) * 16;    // 0,16,32,48
    const unsigned short* kg = qkv + (size_t)(b * 2048 + srow) * 3072 + 1024 + h * 64 + scol;
    const unsigned short* vg = VtG + (size_t)(bh * 64 + srow) * 2048 + scol;
    const size_t kstep = (size_t)64 * 3072;
    unsigned short* wK = &Ks[srow * 72 + scol];
    unsigned short* wV = &Vs[srow * 72 + scol];
    unsigned short* Pw = Ps[wave];

    const float SCL = 0.125f * 1.44269504f;   // dk^-0.5 folded with log2(e)

    // prefetch tile 0
    short8 kr0 = *(const short8*)(kg);
    short8 kr1 = *(const short8*)(kg + 8);
    short8 vr0 = *(const short8*)(vg);
    short8 vr1 = *(const short8*)(vg + 8);

    for (int kt = 0; kt < 32; ++kt) {
        __syncthreads();
        *(short8*)wK = kr0;  *(short8*)(wK + 8) = kr1;
        *(short8*)wV = vr0;  *(short8*)(wV + 8) = vr1;
        if (kt < 31) {   // prefetch next tile; loads stay in flight across the barrier
            kr0 = *(const short8*)(kg + (kt + 1) * kstep);
            kr1 = *(const short8*)(kg + (kt + 1) * kstep + 8);
            vr0 = *(const short8*)(vg + (kt + 1) * 64);
            vr1 = *(const short8*)(vg + (kt + 1) * 64 + 8);
        }
        __syncthreads();

        // QK^T for both q-frags, 4 key subtiles of 16
        f32x4 sA[4], sB[4];
        #pragma unroll
        for (int t = 0; t < 4; ++t) {
            const short8 kb0 = *(const short8*)&Ks[(t * 16 + l16) * 72 + quad * 8];
            const short8 kb1 = *(const short8*)&Ks[(t * 16 + l16) * 72 + 32 + quad * 8];
            f32x4 z = (f32x4){0.f, 0.f, 0.f, 0.f};
            sA[t] = MFMA16(qa1, kb1, MFMA16(qa0, kb0, z));
            sB[t] = MFMA16(qb1, kb1, MFMA16(qb0, kb0, z));
        }

        // ---- frag A: exp, sum, P->LDS, PV ----
        #pragma unroll
        for (int t = 0; t < 4; ++t) {
            const int mk = maskS[kt * 64 + t * 16 + l16];
            #pragma unroll
            for (int r = 0; r < 4; ++r) {
                float p = exp2f(sA[t][r] * SCL);
                p = mk ? 1.0f : p;
                const unsigned pu = f_as_u(p);
                lA[r] += u_as_f(pu & 0xFFFF0000u);          // sum the truncated value
                Pw[(quad * 4 + r) * 68 + t * 16 + l16] = (unsigned short)(pu >> 16);
            }
        }
        __builtin_amdgcn_s_waitcnt(0xC07F);   // lgkmcnt(0): same-wave P visibility
        {
            const short8 pa0 = *(const short8*)&Pw[l16 * 68 + quad * 8];
            const short8 pa1 = *(const short8*)&Pw[l16 * 68 + 32 + quad * 8];
            #pragma unroll
            for (int n = 0; n < 4; ++n) {
                const short8 vb0 = *(const short8*)&Vs[(n * 16 + l16) * 72 + quad * 8];
                const short8 vb1 = *(const short8*)&Vs[(n * 16 + l16) * 72 + 32 + quad * 8];
                oA[n] = MFMA16(pa0, vb0, oA[n]);
                oA[n] = MFMA16(pa1, vb1, oA[n]);
            }
        }

        // ---- frag B ----
        #pragma unroll
        for (int t = 0; t < 4; ++t) {
            const int mk = maskS[kt * 64 + t * 16 + l16];
            #pragma unroll
            for (int r = 0; r < 4; ++r) {
                float p = exp2f(sB[t][r] * SCL);
                p = mk ? 1.0f : p;
                const unsigned pu = f_as_u(p);
                lB[r] += u_as_f(pu & 0xFFFF0000u);
                Pw[(quad * 4 + r) * 68 + t * 16 + l16] = (unsigned short)(pu >> 16);
            }
        }
        __builtin_amdgcn_s_waitcnt(0xC07F);
        {
            const short8 pa0 = *(const short8*)&Pw[l16 * 68 + quad * 8];
            const short8 pa1 = *(const short8*)&Pw[l16 * 68 + 32 + quad * 8];
            #pragma unroll
            for (int n = 0; n < 4; ++n) {
                const short8 vb0 = *(const short8*)&Vs[(n * 16 + l16) * 72 + quad * 8];
                const short8 vb1 = *(const short8*)&Vs[(n * 16 + l16) * 72 + 32 + quad * 8];
                oB[n] = MFMA16(pa0, vb0, oB[n]);
                oB[n] = MFMA16(pa1, vb1, oB[n]);
            }
        }
    }

    #pragma unroll
    for (int d = 1; d < 16; d <<= 1)
        #pragma unroll
        for (int r = 0; r < 4; r++) {
            lA[r] += __shfl_xor(lA[r], d, 16);
            lB[r] += __shfl_xor(lB[r], d, 16);
        }
    #pragma unroll
    for (int r = 0; r < 4; r++) { lA[r] = 1.0f / lA[r]; lB[r] = 1.0f / lB[r]; }
    #pragma unroll
    for (int n = 0; n < 4; n++)
        #pragma unroll
        for (int r = 0; r < 4; r++) {
            const int rowA = qt * 128 + wave * 16 + quad * 4 + r;
            out[(size_t)(b * 2048 + rowA) * 1024 + h * 64 + n * 16 + l16] = f2b(oA[n][r] * lA[r]);
            out[(size_t)(b * 2048 + rowA + 64) * 1024 + h * 64 + n * 16 + l16] = f2b(oB[n][r] * lB[r]);
        }
}

// ---------------------------------------------------------------------------
extern "C" void kernel_launch(void* const* d_in, const int* in_sizes, int n_in,
                              void* d_out, int out_size, void* d_ws, size_t ws_size,
                              hipStream_t stream) {
    const void* x  = d_in[0];
    const int*  mk = (const int*)d_in[1];
    const void* Wq = d_in[2]; const void* bq = d_in[3];
    const void* Wk = d_in[4]; const void* bk = d_in[5];
    const void* Wv = d_in[6]; const void* bv = d_in[7];
    const void* Wo = d_in[8]; const void* bo = d_in[9];

    char* wsb = (char*)d_ws;
    int* flag = (int*)wsb;                                   // 64B header
    unsigned short* W0 = (unsigned short*)(wsb + 64);

    const size_t M1 = 1024u * 1024u;
    const size_t M4 = 4096u * 1024u;
    unsigned short* xb  = W0;                                // 4M elems (reused as abf)
    unsigned short* WT  = xb + M4;                           // 3M: Wq^T|Wk^T|Wv^T
    unsigned short* WoT = WT + 3 * M1;                       // 1M
    unsigned short* b3  = WoT + M1;                          // 3072 (pad 4096)
    unsigned short* bob = b3 + 4096;                         // 1024
    unsigned short* qkv = bob + 1024;                        // 12M
    unsigned short* VtG = qkv + (size_t)4096 * 3072;         // 4M  (total ~48MB)
    unsigned short* abf = xb;                                // alias: x dead after QKV GEMM

    detect_dtype<<<1, 256, 0, stream>>>((const unsigned short*)x, flag);

    convert_bf16<<<(4194304 + 255) / 256, 256, 0, stream>>>(x, xb, 4194304, flag);
    dim3 tg(16, 16);
    convtrans_k<<<tg, 256, 0, stream>>>(Wq, WT, flag);
    convtrans_k<<<tg, 256, 0, stream>>>(Wk, WT + M1, flag);
    convtrans_k<<<tg, 256, 0, stream>>>(Wv, WT + 2 * M1, flag);
    convtrans_k<<<tg, 256, 0, stream>>>(Wo, WoT, flag);
    convert_bias<<<16, 256, 0, stream>>>(bq, bk, bv, bo, b3, bob, flag);

    gemm_bias_relu<<<dim3(24, 32), 256, 0, stream>>>(xb, WT, b3, qkv, flag, 4096, 3072, 1024, 0);
    vtrans<<<dim3(32, 32), 256, 0, stream>>>(qkv, VtG);
    attn_kernel<<<dim3(16, 32), 256, 0, stream>>>(qkv, VtG, mk, abf);
    gemm_bias_relu<<<dim3(8, 32), 256, 0, stream>>>(abf, WoT, bob, d_out, flag, 4096, 1024, 1024, 1);
}

// Round 6
// 274.199 us; speedup vs baseline: 1.0476x; 1.0476x over previous
//
#include <hip/hip_runtime.h>
#include <stdint.h>

typedef __attribute__((ext_vector_type(8))) short short8;   // 8 bf16 (4 VGPRs)
typedef __attribute__((ext_vector_type(4))) float f32x4;    // MFMA acc

#define MFMA16(a, b, c) __builtin_amdgcn_mfma_f32_16x16x32_bf16((a), (b), (c), 0, 0, 0)

__device__ __forceinline__ float b2f(unsigned short u) {
    union { unsigned u; float f; } c; c.u = ((unsigned)u) << 16; return c.f;
}
__device__ __forceinline__ unsigned short f2b(float f) {
    union { float f; unsigned u; } c; c.f = f;
    unsigned r = c.u + 0x7FFF + ((c.u >> 16) & 1);   // round-to-nearest-even
    return (unsigned short)(r >> 16);
}
__device__ __forceinline__ unsigned f_as_u(float f) {
    union { float f; unsigned u; } c; c.f = f; return c.u;
}
__device__ __forceinline__ float u_as_f(unsigned u) {
    union { unsigned u; float f; } c; c.u = u; return c.f;
}

// async global->LDS, 16B per lane; LDS dest = wave-uniform base + lane*16.
__device__ __forceinline__ void g2lds16(const unsigned short* g, unsigned lds_byte_off) {
    __builtin_amdgcn_global_load_lds(
        (const __attribute__((address_space(1))) void*)(uintptr_t)g,
        (__attribute__((address_space(3))) void*)(uintptr_t)lds_byte_off,
        16, 0, 0);
}

// ---------------------------------------------------------------------------
// Dtype canary (proven): flag=1 => f32 inputs, 0 => bf16.
// ---------------------------------------------------------------------------
__global__ void detect_dtype(const unsigned short* __restrict__ x, int* __restrict__ flag) {
    __shared__ int cnt;
    if (threadIdx.x == 0) cnt = 0;
    __syncthreads();
    int insane = 0;
    #pragma unroll
    for (int j = 0; j < 4; ++j) {
        unsigned short u = x[threadIdx.x * 4 + j];
        int e = (u >> 7) & 0xFF;
        if ((e >= 1 && e <= 90) || e >= 165) insane++;
    }
    atomicAdd(&cnt, insane);
    __syncthreads();
    if (threadIdx.x == 0) *flag = (cnt > 128) ? 1 : 0;
}

__global__ __launch_bounds__(256) void convert_bf16(const void* __restrict__ src,
                                                    unsigned short* __restrict__ dst,
                                                    int n, const int* __restrict__ flag) {
    int i = blockIdx.x * 256 + threadIdx.x;
    if (i >= n) return;
    if (*flag) dst[i] = f2b(((const float*)src)[i]);
    else       dst[i] = ((const unsigned short*)src)[i];
}

// all 4 bias vectors in one launch: grid 16 x 256
__global__ __launch_bounds__(256) void convert_bias(const void* __restrict__ s0, const void* __restrict__ s1,
                                                    const void* __restrict__ s2, const void* __restrict__ s3,
                                                    unsigned short* __restrict__ dstB3,
                                                    unsigned short* __restrict__ dstBo,
                                                    const int* __restrict__ flag) {
    const int which = blockIdx.x >> 2;
    const int i = (blockIdx.x & 3) * 256 + threadIdx.x;
    const void* src = (which == 0) ? s0 : (which == 1) ? s1 : (which == 2) ? s2 : s3;
    unsigned short v = (*flag) ? f2b(((const float*)src)[i]) : ((const unsigned short*)src)[i];
    if (which < 3) dstB3[which * 1024 + i] = v;
    else dstBo[i] = v;
}

// ---------------------------------------------------------------------------
// Fused convert + transpose, all 4 weights in one launch (blockIdx.z picks
// the matrix; dst = WT + z*1M works because WoT directly follows WT).
// ---------------------------------------------------------------------------
__global__ __launch_bounds__(256) void convtrans_k(const void* __restrict__ s0, const void* __restrict__ s1,
                                                   const void* __restrict__ s2, const void* __restrict__ s3,
                                                   unsigned short* __restrict__ dstBase,
                                                   const int* __restrict__ flag) {
    __shared__ __align__(16) unsigned short tile[64 * 72];
    const int z = blockIdx.z;
    const void* src = (z == 0) ? s0 : (z == 1) ? s1 : (z == 2) ? s2 : s3;
    unsigned short* dst = dstBase + (size_t)z * 1024 * 1024;
    const int tid = threadIdx.x;
    const int r0 = blockIdx.y * 64, c0 = blockIdx.x * 64;
    const int rb = tid >> 3, c = (tid & 7) * 8;
    if (*flag) {
        const float* s = (const float*)src;
        #pragma unroll
        for (int it = 0; it < 2; ++it) {
            int rr = it * 32 + rb;
            float4 f0 = *(const float4*)&s[(size_t)(r0 + rr) * 1024 + c0 + c];
            float4 f1 = *(const float4*)&s[(size_t)(r0 + rr) * 1024 + c0 + c + 4];
            unsigned short* t = &tile[rr * 72 + c];
            t[0] = f2b(f0.x); t[1] = f2b(f0.y); t[2] = f2b(f0.z); t[3] = f2b(f0.w);
            t[4] = f2b(f1.x); t[5] = f2b(f1.y); t[6] = f2b(f1.z); t[7] = f2b(f1.w);
        }
    } else {
        const unsigned short* s = (const unsigned short*)src;
        #pragma unroll
        for (int it = 0; it < 2; ++it) {
            int rr = it * 32 + rb;
            *(short8*)&tile[rr * 72 + c] = *(const short8*)&s[(size_t)(r0 + rr) * 1024 + c0 + c];
        }
    }
    __syncthreads();
    #pragma unroll
    for (int it = 0; it < 2; ++it) {
        int n = it * 32 + rb, k8 = c;
        union { short8 s; unsigned short u[8]; } tmp;
        #pragma unroll
        for (int j = 0; j < 8; ++j) tmp.u[j] = tile[(k8 + j) * 72 + n];
        *(short8*)&dst[(size_t)(c0 + n) * 1024 + r0 + k8] = tmp.s;
    }
}

// ---------------------------------------------------------------------------
// V transpose: qkv [4096][3072] (v slice) -> VtG [bh][dk][seq]
// ---------------------------------------------------------------------------
__global__ __launch_bounds__(256) void vtrans(const unsigned short* __restrict__ qkv,
                                              unsigned short* __restrict__ VtG) {
    __shared__ __align__(16) unsigned short tile[64 * 72];
    const int st = blockIdx.x, bh = blockIdx.y;
    const int b = bh >> 4, h = bh & 15;
    const int tid = threadIdx.x;
    const int rb = tid >> 3, c = (tid & 7) * 8;
    #pragma unroll
    for (int it = 0; it < 2; ++it) {
        int r = it * 32 + rb;
        *(short8*)&tile[r * 72 + c] =
            *(const short8*)&qkv[(size_t)(b * 2048 + st * 64 + r) * 3072 + 2048 + h * 64 + c];
    }
    __syncthreads();
    #pragma unroll
    for (int it = 0; it < 2; ++it) {
        int n = it * 32 + rb;
        union { short8 s; unsigned short u[8]; } tmp;
        #pragma unroll
        for (int j = 0; j < 8; ++j) tmp.u[j] = tile[(c + j) * 72 + n];
        *(short8*)&VtG[(size_t)(bh * 64 + n) * 2048 + st * 64 + c] = tmp.s;
    }
}

// ---------------------------------------------------------------------------
// C = relu(A[M,K] @ BT[N,K]^T + bias[N]); m97 structure (round-5 proven).
// ---------------------------------------------------------------------------
__global__ __launch_bounds__(256) void gemm_bias_relu(const unsigned short* __restrict__ A,
                                                      const unsigned short* __restrict__ BT,
                                                      const unsigned short* __restrict__ bias,
                                                      void* __restrict__ C,
                                                      const int* __restrict__ flag,
                                                      int M, int N, int K, int out_is_final) {
    __shared__ __align__(16) unsigned short As[128 * 32];
    __shared__ __align__(16) unsigned short Bs[128 * 32];
    const int tid = threadIdx.x;
    const int wave = tid >> 6, lane = tid & 63;
    const int quad = lane >> 4, l16 = lane & 15;
    const int wm = wave >> 1, wn = wave & 1;
    const int m0 = blockIdx.y * 128, n0 = blockIdx.x * 128;

    f32x4 acc[4][4];
    #pragma unroll
    for (int i = 0; i < 4; i++)
        #pragma unroll
        for (int j = 0; j < 4; j++) acc[i][j] = (f32x4){0.f, 0.f, 0.f, 0.f};

    const int srow = wave * 32 + (lane >> 2);
    const int sc8  = (lane & 3) * 8;
    const unsigned short* gA0 = A  + (size_t)(m0 + srow) * K + sc8;
    const unsigned short* gA1 = gA0 + (size_t)16 * K;
    const unsigned short* gB0 = BT + (size_t)(n0 + srow) * K + sc8;
    const unsigned short* gB1 = gB0 + (size_t)16 * K;
    const unsigned ldsA = (unsigned)(uintptr_t)&As[0] + wave * 2048;
    const unsigned ldsB = (unsigned)(uintptr_t)&Bs[0] + wave * 2048;

    for (int k0 = 0; k0 < K; k0 += 32) {
        __syncthreads();
        g2lds16(gA0 + k0, ldsA);
        g2lds16(gA1 + k0, ldsA + 1024);
        g2lds16(gB0 + k0, ldsB);
        g2lds16(gB1 + k0, ldsB + 1024);
        __syncthreads();
        short8 af[4], bf[4];
        #pragma unroll
        for (int i = 0; i < 4; i++) af[i] = *(const short8*)&As[(wm * 64 + i * 16 + l16) * 32 + quad * 8];
        #pragma unroll
        for (int j = 0; j < 4; j++) bf[j] = *(const short8*)&Bs[(wn * 64 + j * 16 + l16) * 32 + quad * 8];
        #pragma unroll
        for (int i = 0; i < 4; i++)
            #pragma unroll
            for (int j = 0; j < 4; j++)
                acc[i][j] = MFMA16(af[i], bf[j], acc[i][j]);
    }

    const int f32out = out_is_final && (*flag != 0);
    #pragma unroll
    for (int j = 0; j < 4; j++) {
        const int col = n0 + wn * 64 + j * 16 + l16;
        const float bj = b2f(bias[col]);
        #pragma unroll
        for (int i = 0; i < 4; i++) {
            const int rowb = m0 + wm * 64 + i * 16 + quad * 4;
            #pragma unroll
            for (int r = 0; r < 4; r++) {
                float v = acc[i][j][r] + bj;
                v = v > 0.f ? v : 0.f;
                if (f32out) ((float*)C)[(size_t)(rowb + r) * N + col] = v;
                else ((unsigned short*)C)[(size_t)(rowb + r) * N + col] = f2b(v);
            }
        }
    }
}

// ---------------------------------------------------------------------------
// Attention: no-max softmax + deferred row-sum (round-4 proven math).
// 512 threads = 8 waves per block, ONE 16-row q-frag per wave (2x the
// resident waves of round 4 to hide exp/LDS latency). 64-key tiles.
// Plain staging loads (round-5 register prefetch regressed -> reverted).
// ---------------------------------------------------------------------------
__global__ __launch_bounds__(512) void attn_kernel(const unsigned short* __restrict__ qkv,
                                                   const unsigned short* __restrict__ VtG,
                                                   const int* __restrict__ mask,
                                                   unsigned short* __restrict__ out) {
    __shared__ __align__(16) unsigned short Ks[64 * 72];    // [key][dk]
    __shared__ __align__(16) unsigned short Vs[64 * 72];    // [dk][key]
    __shared__ __align__(16) unsigned short Ps[8][16 * 68]; // per-wave P; stride 68: write-conflict-free
    __shared__ int maskS[2048];

    const int qt = blockIdx.x, bh = blockIdx.y;
    const int b = bh >> 4, h = bh & 15;
    const int tid = threadIdx.x, wave = tid >> 6, lane = tid & 63;
    const int quad = lane >> 4, l16 = lane & 15;

    for (int i = tid; i < 2048; i += 512) maskS[i] = mask[b * 2048 + i];

    const int qrow = qt * 128 + wave * 16 + l16;
    const unsigned short* qp = qkv + (size_t)(b * 2048 + qrow) * 3072 + h * 64;
    const short8 qa0 = *(const short8*)(qp + quad * 8);
    const short8 qa1 = *(const short8*)(qp + 32 + quad * 8);

    f32x4 oA[4];
    float lA[4];
    #pragma unroll
    for (int n = 0; n < 4; n++) oA[n] = (f32x4){0.f, 0.f, 0.f, 0.f};
    #pragma unroll
    for (int r = 0; r < 4; r++) lA[r] = 0.f;

    const int srow = tid >> 3;          // 0..63
    const int scol = (tid & 7) * 8;     // 0..56
    const unsigned short* kg = qkv + (size_t)(b * 2048 + srow) * 3072 + 1024 + h * 64 + scol;
    const unsigned short* vg = VtG + (size_t)(bh * 64 + srow) * 2048 + scol;
    const size_t kstep = (size_t)64 * 3072;
    unsigned short* wK = &Ks[srow * 72 + scol];
    unsigned short* wV = &Vs[srow * 72 + scol];
    unsigned short* Pw = Ps[wave];

    const float SCL = 0.125f * 1.44269504f;   // dk^-0.5 folded with log2(e)

    for (int kt = 0; kt < 32; ++kt) {
        __syncthreads();
        *(short8*)wK = *(const short8*)(kg + kt * kstep);
        *(short8*)wV = *(const short8*)(vg + kt * 64);
        __syncthreads();

        // QK^T: 4 key subtiles of 16
        f32x4 sA[4];
        #pragma unroll
        for (int t = 0; t < 4; ++t) {
            const short8 kb0 = *(const short8*)&Ks[(t * 16 + l16) * 72 + quad * 8];
            const short8 kb1 = *(const short8*)&Ks[(t * 16 + l16) * 72 + 32 + quad * 8];
            f32x4 z = (f32x4){0.f, 0.f, 0.f, 0.f};
            sA[t] = MFMA16(qa1, kb1, MFMA16(qa0, kb0, z));
        }

        // exp, sum, P->LDS (stride 68), PV
        #pragma unroll
        for (int t = 0; t < 4; ++t) {
            const int mk = maskS[kt * 64 + t * 16 + l16];
            #pragma unroll
            for (int r = 0; r < 4; ++r) {
                float p = exp2f(sA[t][r] * SCL);
                p = mk ? 1.0f : p;
                const unsigned pu = f_as_u(p);
                lA[r] += u_as_f(pu & 0xFFFF0000u);          // sum the truncated value
                Pw[(quad * 4 + r) * 68 + t * 16 + l16] = (unsigned short)(pu >> 16);
            }
        }
        __builtin_amdgcn_s_waitcnt(0xC07F);   // lgkmcnt(0): same-wave P visibility
        {
            const short8 pa0 = *(const short8*)&Pw[l16 * 68 + quad * 8];
            const short8 pa1 = *(const short8*)&Pw[l16 * 68 + 32 + quad * 8];
            #pragma unroll
            for (int n = 0; n < 4; ++n) {
                const short8 vb0 = *(const short8*)&Vs[(n * 16 + l16) * 72 + quad * 8];
                const short8 vb1 = *(const short8*)&Vs[(n * 16 + l16) * 72 + 32 + quad * 8];
                oA[n] = MFMA16(pa0, vb0, oA[n]);
                oA[n] = MFMA16(pa1, vb1, oA[n]);
            }
        }
    }

    #pragma unroll
    for (int d = 1; d < 16; d <<= 1)
        #pragma unroll
        for (int r = 0; r < 4; r++) lA[r] += __shfl_xor(lA[r], d, 16);
    #pragma unroll
    for (int r = 0; r < 4; r++) lA[r] = 1.0f / lA[r];
    #pragma unroll
    for (int n = 0; n < 4; n++)
        #pragma unroll
        for (int r = 0; r < 4; r++) {
            const int row = qt * 128 + wave * 16 + quad * 4 + r;
            out[(size_t)(b * 2048 + row) * 1024 + h * 64 + n * 16 + l16] = f2b(oA[n][r] * lA[r]);
        }
}

// ---------------------------------------------------------------------------
extern "C" void kernel_launch(void* const* d_in, const int* in_sizes, int n_in,
                              void* d_out, int out_size, void* d_ws, size_t ws_size,
                              hipStream_t stream) {
    const void* x  = d_in[0];
    const int*  mk = (const int*)d_in[1];
    const void* Wq = d_in[2]; const void* bq = d_in[3];
    const void* Wk = d_in[4]; const void* bk = d_in[5];
    const void* Wv = d_in[6]; const void* bv = d_in[7];
    const void* Wo = d_in[8]; const void* bo = d_in[9];

    char* wsb = (char*)d_ws;
    int* flag = (int*)wsb;                                   // 64B header
    unsigned short* W0 = (unsigned short*)(wsb + 64);

    const size_t M1 = 1024u * 1024u;
    const size_t M4 = 4096u * 1024u;
    unsigned short* xb  = W0;                                // 4M elems (reused as abf)
    unsigned short* WT  = xb + M4;                           // 3M: Wq^T|Wk^T|Wv^T
    unsigned short* WoT = WT + 3 * M1;                       // 1M (contiguous after WT)
    unsigned short* b3  = WoT + M1;                          // 3072 (pad 4096)
    unsigned short* bob = b3 + 4096;                         // 1024
    unsigned short* qkv = bob + 1024;                        // 12M
    unsigned short* VtG = qkv + (size_t)4096 * 3072;         // 4M  (total ~48MB)
    unsigned short* abf = xb;                                // alias: x dead after QKV GEMM

    detect_dtype<<<1, 256, 0, stream>>>((const unsigned short*)x, flag);

    convert_bf16<<<(4194304 + 255) / 256, 256, 0, stream>>>(x, xb, 4194304, flag);
    convtrans_k<<<dim3(16, 16, 4), 256, 0, stream>>>(Wq, Wk, Wv, Wo, WT, flag);
    convert_bias<<<16, 256, 0, stream>>>(bq, bk, bv, bo, b3, bob, flag);

    gemm_bias_relu<<<dim3(24, 32), 256, 0, stream>>>(xb, WT, b3, qkv, flag, 4096, 3072, 1024, 0);
    vtrans<<<dim3(32, 32), 256, 0, stream>>>(qkv, VtG);
    attn_kernel<<<dim3(16, 32), 512, 0, stream>>>(qkv, VtG, mk, abf);
    gemm_bias_relu<<<dim3(8, 32), 256, 0, stream>>>(abf, WoT, bob, d_out, flag, 4096, 1024, 1024, 1);
}

// Round 7
// 265.989 us; speedup vs baseline: 1.0800x; 1.0309x over previous
//
#include <hip/hip_runtime.h>
#include <stdint.h>

typedef __attribute__((ext_vector_type(8))) short short8;   // 8 bf16 (4 VGPRs)
typedef __attribute__((ext_vector_type(4))) float f32x4;    // MFMA acc
typedef __attribute__((ext_vector_type(4))) unsigned short ushort4_t;

#define MFMA16(a, b, c) __builtin_amdgcn_mfma_f32_16x16x32_bf16((a), (b), (c), 0, 0, 0)

__device__ __forceinline__ float b2f(unsigned short u) {
    union { unsigned u; float f; } c; c.u = ((unsigned)u) << 16; return c.f;
}
__device__ __forceinline__ unsigned short f2b(float f) {
    union { float f; unsigned u; } c; c.f = f;
    unsigned r = c.u + 0x7FFF + ((c.u >> 16) & 1);   // round-to-nearest-even
    return (unsigned short)(r >> 16);
}
__device__ __forceinline__ unsigned f_as_u(float f) {
    union { float f; unsigned u; } c; c.f = f; return c.u;
}
__device__ __forceinline__ float u_as_f(unsigned u) {
    union { unsigned u; float f; } c; c.u = u; return c.f;
}

// async global->LDS, 16B per lane; LDS dest = wave-uniform base + lane*16.
__device__ __forceinline__ void g2lds16(const unsigned short* g, unsigned lds_byte_off) {
    __builtin_amdgcn_global_load_lds(
        (const __attribute__((address_space(1))) void*)(uintptr_t)g,
        (__attribute__((address_space(3))) void*)(uintptr_t)lds_byte_off,
        16, 0, 0);
}

// ---------------------------------------------------------------------------
// Dtype canary (proven): flag=1 => f32 inputs, 0 => bf16.
// ---------------------------------------------------------------------------
__global__ void detect_dtype(const unsigned short* __restrict__ x, int* __restrict__ flag) {
    __shared__ int cnt;
    if (threadIdx.x == 0) cnt = 0;
    __syncthreads();
    int insane = 0;
    #pragma unroll
    for (int j = 0; j < 4; ++j) {
        unsigned short u = x[threadIdx.x * 4 + j];
        int e = (u >> 7) & 0xFF;
        if ((e >= 1 && e <= 90) || e >= 165) insane++;
    }
    atomicAdd(&cnt, insane);
    __syncthreads();
    if (threadIdx.x == 0) *flag = (cnt > 128) ? 1 : 0;
}

__global__ __launch_bounds__(256) void convert_bf16(const void* __restrict__ src,
                                                    unsigned short* __restrict__ dst,
                                                    int n, const int* __restrict__ flag) {
    int i = blockIdx.x * 256 + threadIdx.x;
    if (i >= n) return;
    if (*flag) dst[i] = f2b(((const float*)src)[i]);
    else       dst[i] = ((const unsigned short*)src)[i];
}

// all 4 bias vectors in one launch: grid 16 x 256
__global__ __launch_bounds__(256) void convert_bias(const void* __restrict__ s0, const void* __restrict__ s1,
                                                    const void* __restrict__ s2, const void* __restrict__ s3,
                                                    unsigned short* __restrict__ dstB3,
                                                    unsigned short* __restrict__ dstBo,
                                                    const int* __restrict__ flag) {
    const int which = blockIdx.x >> 2;
    const int i = (blockIdx.x & 3) * 256 + threadIdx.x;
    const void* src = (which == 0) ? s0 : (which == 1) ? s1 : (which == 2) ? s2 : s3;
    unsigned short v = (*flag) ? f2b(((const float*)src)[i]) : ((const unsigned short*)src)[i];
    if (which < 3) dstB3[which * 1024 + i] = v;
    else dstBo[i] = v;
}

// ---------------------------------------------------------------------------
// Fused convert + transpose, all 4 weights in one launch (z picks matrix).
// ---------------------------------------------------------------------------
__global__ __launch_bounds__(256) void convtrans_k(const void* __restrict__ s0, const void* __restrict__ s1,
                                                   const void* __restrict__ s2, const void* __restrict__ s3,
                                                   unsigned short* __restrict__ dstBase,
                                                   const int* __restrict__ flag) {
    __shared__ __align__(16) unsigned short tile[64 * 72];
    const int z = blockIdx.z;
    const void* src = (z == 0) ? s0 : (z == 1) ? s1 : (z == 2) ? s2 : s3;
    unsigned short* dst = dstBase + (size_t)z * 1024 * 1024;
    const int tid = threadIdx.x;
    const int r0 = blockIdx.y * 64, c0 = blockIdx.x * 64;
    const int rb = tid >> 3, c = (tid & 7) * 8;
    if (*flag) {
        const float* s = (const float*)src;
        #pragma unroll
        for (int it = 0; it < 2; ++it) {
            int rr = it * 32 + rb;
            float4 f0 = *(const float4*)&s[(size_t)(r0 + rr) * 1024 + c0 + c];
            float4 f1 = *(const float4*)&s[(size_t)(r0 + rr) * 1024 + c0 + c + 4];
            unsigned short* t = &tile[rr * 72 + c];
            t[0] = f2b(f0.x); t[1] = f2b(f0.y); t[2] = f2b(f0.z); t[3] = f2b(f0.w);
            t[4] = f2b(f1.x); t[5] = f2b(f1.y); t[6] = f2b(f1.z); t[7] = f2b(f1.w);
        }
    } else {
        const unsigned short* s = (const unsigned short*)src;
        #pragma unroll
        for (int it = 0; it < 2; ++it) {
            int rr = it * 32 + rb;
            *(short8*)&tile[rr * 72 + c] = *(const short8*)&s[(size_t)(r0 + rr) * 1024 + c0 + c];
        }
    }
    __syncthreads();
    #pragma unroll
    for (int it = 0; it < 2; ++it) {
        int n = it * 32 + rb, k8 = c;
        union { short8 s; unsigned short u[8]; } tmp;
        #pragma unroll
        for (int j = 0; j < 8; ++j) tmp.u[j] = tile[(k8 + j) * 72 + n];
        *(short8*)&dst[(size_t)(c0 + n) * 1024 + r0 + k8] = tmp.s;
    }
}

// ---------------------------------------------------------------------------
// C = relu(A[M,K] @ BT[N,K]^T + bias[N]); m97 staging.
// mode 0: bf16 row-major store. mode 1: final, honors *flag (f32/bf16).
// mode 2: QKV — blocks with n0>=2048 (V columns) store TRANSPOSED to
//         VtG[bh][dk][seq] (packed ushort4 along seq); q/k stored normally.
// ---------------------------------------------------------------------------
__global__ __launch_bounds__(256) void gemm_bias_relu(const unsigned short* __restrict__ A,
                                                      const unsigned short* __restrict__ BT,
                                                      const unsigned short* __restrict__ bias,
                                                      void* __restrict__ C,
                                                      unsigned short* __restrict__ VtG,
                                                      const int* __restrict__ flag,
                                                      int M, int N, int K, int mode) {
    __shared__ __align__(16) unsigned short As[128 * 32];
    __shared__ __align__(16) unsigned short Bs[128 * 32];
    const int tid = threadIdx.x;
    const int wave = tid >> 6, lane = tid & 63;
    const int quad = lane >> 4, l16 = lane & 15;
    const int wm = wave >> 1, wn = wave & 1;
    const int m0 = blockIdx.y * 128, n0 = blockIdx.x * 128;

    f32x4 acc[4][4];
    #pragma unroll
    for (int i = 0; i < 4; i++)
        #pragma unroll
        for (int j = 0; j < 4; j++) acc[i][j] = (f32x4){0.f, 0.f, 0.f, 0.f};

    const int srow = wave * 32 + (lane >> 2);
    const int sc8  = (lane & 3) * 8;
    const unsigned short* gA0 = A  + (size_t)(m0 + srow) * K + sc8;
    const unsigned short* gA1 = gA0 + (size_t)16 * K;
    const unsigned short* gB0 = BT + (size_t)(n0 + srow) * K + sc8;
    const unsigned short* gB1 = gB0 + (size_t)16 * K;
    const unsigned ldsA = (unsigned)(uintptr_t)&As[0] + wave * 2048;
    const unsigned ldsB = (unsigned)(uintptr_t)&Bs[0] + wave * 2048;

    for (int k0 = 0; k0 < K; k0 += 32) {
        __syncthreads();
        g2lds16(gA0 + k0, ldsA);
        g2lds16(gA1 + k0, ldsA + 1024);
        g2lds16(gB0 + k0, ldsB);
        g2lds16(gB1 + k0, ldsB + 1024);
        __syncthreads();
        short8 af[4], bf[4];
        #pragma unroll
        for (int i = 0; i < 4; i++) af[i] = *(const short8*)&As[(wm * 64 + i * 16 + l16) * 32 + quad * 8];
        #pragma unroll
        for (int j = 0; j < 4; j++) bf[j] = *(const short8*)&Bs[(wn * 64 + j * 16 + l16) * 32 + quad * 8];
        #pragma unroll
        for (int i = 0; i < 4; i++)
            #pragma unroll
            for (int j = 0; j < 4; j++)
                acc[i][j] = MFMA16(af[i], bf[j], acc[i][j]);
    }

    if (mode == 2 && n0 >= 2048) {
        // V columns: write transposed into VtG[bh][dk][seq]
        #pragma unroll
        for (int j = 0; j < 4; j++) {
            const int col = n0 + wn * 64 + j * 16 + l16;       // 2048..3071
            const int h  = (col - 2048) >> 6;
            const int dk = (col - 2048) & 63;
            const float bj = b2f(bias[col]);
            #pragma unroll
            for (int i = 0; i < 4; i++) {
                const int rowb = m0 + wm * 64 + i * 16 + quad * 4;   // global seq (0..4095)
                const int bb = rowb >> 11;
                const int s0 = rowb & 2047;
                ushort4_t w;
                #pragma unroll
                for (int r = 0; r < 4; r++) {
                    float v = acc[i][j][r] + bj;
                    v = v > 0.f ? v : 0.f;
                    w[r] = f2b(v);
                }
                *(ushort4_t*)&VtG[(size_t)((bb * 16 + h) * 64 + dk) * 2048 + s0] = w;
            }
        }
    } else {
        const int f32out = (mode == 1) && (*flag != 0);
        #pragma unroll
        for (int j = 0; j < 4; j++) {
            const int col = n0 + wn * 64 + j * 16 + l16;
            const float bj = b2f(bias[col]);
            #pragma unroll
            for (int i = 0; i < 4; i++) {
                const int rowb = m0 + wm * 64 + i * 16 + quad * 4;
                #pragma unroll
                for (int r = 0; r < 4; r++) {
                    float v = acc[i][j][r] + bj;
                    v = v > 0.f ? v : 0.f;
                    if (f32out) ((float*)C)[(size_t)(rowb + r) * N + col] = v;
                    else ((unsigned short*)C)[(size_t)(rowb + r) * N + col] = f2b(v);
                }
            }
        }
    }
}

// ---------------------------------------------------------------------------
// Attention: no-max softmax + deferred row-sum. 256 thr / 4 waves; TWO
// 16-row q-frags per wave (independent chains = ILP — round-4 structure),
// dual P buffers with a single LDS drain per tile, Vs fragments cached in
// registers and shared across both frags. 64-key tiles, stride-68 P.
// ---------------------------------------------------------------------------
__global__ __launch_bounds__(256) void attn_kernel(const unsigned short* __restrict__ qkv,
                                                   const unsigned short* __restrict__ VtG,
                                                   const int* __restrict__ mask,
                                                   unsigned short* __restrict__ out) {
    __shared__ __align__(16) unsigned short Ks[64 * 72];       // [key][dk]
    __shared__ __align__(16) unsigned short Vs[64 * 72];       // [dk][key]
    __shared__ __align__(16) unsigned short Ps[4][2][16 * 68]; // per-wave, per-frag P
    __shared__ unsigned char maskB[2048];

    const int qt = blockIdx.x, bh = blockIdx.y;
    const int b = bh >> 4, h = bh & 15;
    const int tid = threadIdx.x, wave = tid >> 6, lane = tid & 63;
    const int quad = lane >> 4, l16 = lane & 15;

    for (int i = tid; i < 2048; i += 256) maskB[i] = (unsigned char)(mask[b * 2048 + i] != 0);

    const int qrowA = qt * 128 + wave * 16 + l16;
    const unsigned short* qpA = qkv + (size_t)(b * 2048 + qrowA) * 3072 + h * 64;
    const unsigned short* qpB = qpA + (size_t)64 * 3072;
    const short8 qa0 = *(const short8*)(qpA + quad * 8);
    const short8 qa1 = *(const short8*)(qpA + 32 + quad * 8);
    const short8 qb0 = *(const short8*)(qpB + quad * 8);
    const short8 qb1 = *(const short8*)(qpB + 32 + quad * 8);

    f32x4 oA[4], oB[4];
    float lA[4], lB[4];
    #pragma unroll
    for (int n = 0; n < 4; n++) { oA[n] = (f32x4){0.f,0.f,0.f,0.f}; oB[n] = (f32x4){0.f,0.f,0.f,0.f}; }
    #pragma unroll
    for (int r = 0; r < 4; r++) { lA[r] = 0.f; lB[r] = 0.f; }

    const int srow = tid >> 2;          // 0..63
    const int scol = (tid & 3) * 16;    // 0,16,32,48
    const unsigned short* kg = qkv + (size_t)(b * 2048 + srow) * 3072 + 1024 + h * 64 + scol;
    const unsigned short* vg = VtG + (size_t)(bh * 64 + srow) * 2048 + scol;
    const size_t kstep = (size_t)64 * 3072;
    unsigned short* wK = &Ks[srow * 72 + scol];
    unsigned short* wV = &Vs[srow * 72 + scol];
    unsigned short* PwA = Ps[wave][0];
    unsigned short* PwB = Ps[wave][1];

    const float SCL = 0.125f * 1.44269504f;   // dk^-0.5 folded with log2(e)

    for (int kt = 0; kt < 32; ++kt) {
        __syncthreads();
        *(short8*)wK       = *(const short8*)(kg + kt * kstep);
        *(short8*)(wK + 8) = *(const short8*)(kg + kt * kstep + 8);
        *(short8*)wV       = *(const short8*)(vg + kt * 64);
        *(short8*)(wV + 8) = *(const short8*)(vg + kt * 64 + 8);
        __syncthreads();

        // QK^T for both frags (K fragments shared)
        f32x4 sA[4], sB[4];
        #pragma unroll
        for (int t = 0; t < 4; ++t) {
            const short8 kb0 = *(const short8*)&Ks[(t * 16 + l16) * 72 + quad * 8];
            const short8 kb1 = *(const short8*)&Ks[(t * 16 + l16) * 72 + 32 + quad * 8];
            f32x4 z = (f32x4){0.f, 0.f, 0.f, 0.f};
            sA[t] = MFMA16(qa1, kb1, MFMA16(qa0, kb0, z));
            sB[t] = MFMA16(qb1, kb1, MFMA16(qb0, kb0, z));
        }

        // cache V fragments once; reused by both frags
        short8 vb[4][2];
        #pragma unroll
        for (int n = 0; n < 4; ++n) {
            vb[n][0] = *(const short8*)&Vs[(n * 16 + l16) * 72 + quad * 8];
            vb[n][1] = *(const short8*)&Vs[(n * 16 + l16) * 72 + 32 + quad * 8];
        }

        // exp + P-write frag A; exp-B compute hides P_A write latency
        #pragma unroll
        for (int t = 0; t < 4; ++t) {
            const int mk = maskB[kt * 64 + t * 16 + l16];
            #pragma unroll
            for (int r = 0; r < 4; ++r) {
                float p = exp2f(sA[t][r] * SCL);
                p = mk ? 1.0f : p;
                const unsigned pu = f_as_u(p);
                lA[r] += u_as_f(pu & 0xFFFF0000u);
                PwA[(quad * 4 + r) * 68 + t * 16 + l16] = (unsigned short)(pu >> 16);
            }
        }
        #pragma unroll
        for (int t = 0; t < 4; ++t) {
            const int mk = maskB[kt * 64 + t * 16 + l16];
            #pragma unroll
            for (int r = 0; r < 4; ++r) {
                float p = exp2f(sB[t][r] * SCL);
                p = mk ? 1.0f : p;
                const unsigned pu = f_as_u(p);
                lB[r] += u_as_f(pu & 0xFFFF0000u);
                PwB[(quad * 4 + r) * 68 + t * 16 + l16] = (unsigned short)(pu >> 16);
            }
        }
        __builtin_amdgcn_s_waitcnt(0xC07F);   // single lgkmcnt(0) drain for both P buffers

        {
            const short8 paA0 = *(const short8*)&PwA[l16 * 68 + quad * 8];
            const short8 paA1 = *(const short8*)&PwA[l16 * 68 + 32 + quad * 8];
            const short8 paB0 = *(const short8*)&PwB[l16 * 68 + quad * 8];
            const short8 paB1 = *(const short8*)&PwB[l16 * 68 + 32 + quad * 8];
            #pragma unroll
            for (int n = 0; n < 4; ++n) {
                oA[n] = MFMA16(paA0, vb[n][0], oA[n]);
                oA[n] = MFMA16(paA1, vb[n][1], oA[n]);
                oB[n] = MFMA16(paB0, vb[n][0], oB[n]);
                oB[n] = MFMA16(paB1, vb[n][1], oB[n]);
            }
        }
    }

    #pragma unroll
    for (int d = 1; d < 16; d <<= 1)
        #pragma unroll
        for (int r = 0; r < 4; r++) {
            lA[r] += __shfl_xor(lA[r], d, 16);
            lB[r] += __shfl_xor(lB[r], d, 16);
        }
    #pragma unroll
    for (int r = 0; r < 4; r++) { lA[r] = 1.0f / lA[r]; lB[r] = 1.0f / lB[r]; }
    #pragma unroll
    for (int n = 0; n < 4; n++)
        #pragma unroll
        for (int r = 0; r < 4; r++) {
            const int row = qt * 128 + wave * 16 + quad * 4 + r;
            out[(size_t)(b * 2048 + row) * 1024 + h * 64 + n * 16 + l16] = f2b(oA[n][r] * lA[r]);
            out[(size_t)(b * 2048 + row + 64) * 1024 + h * 64 + n * 16 + l16] = f2b(oB[n][r] * lB[r]);
        }
}

// ---------------------------------------------------------------------------
extern "C" void kernel_launch(void* const* d_in, const int* in_sizes, int n_in,
                              void* d_out, int out_size, void* d_ws, size_t ws_size,
                              hipStream_t stream) {
    const void* x  = d_in[0];
    const int*  mk = (const int*)d_in[1];
    const void* Wq = d_in[2]; const void* bq = d_in[3];
    const void* Wk = d_in[4]; const void* bk = d_in[5];
    const void* Wv = d_in[6]; const void* bv = d_in[7];
    const void* Wo = d_in[8]; const void* bo = d_in[9];

    char* wsb = (char*)d_ws;
    int* flag = (int*)wsb;                                   // 64B header
    unsigned short* W0 = (unsigned short*)(wsb + 64);

    const size_t M1 = 1024u * 1024u;
    const size_t M4 = 4096u * 1024u;
    unsigned short* xb  = W0;                                // 4M elems (reused as abf)
    unsigned short* WT  = xb + M4;                           // 3M: Wq^T|Wk^T|Wv^T
    unsigned short* WoT = WT + 3 * M1;                       // 1M (contiguous after WT)
    unsigned short* b3  = WoT + M1;                          // 3072 (pad 4096)
    unsigned short* bob = b3 + 4096;                         // 1024
    unsigned short* qkv = bob + 1024;                        // 12M (V third unused now)
    unsigned short* VtG = qkv + (size_t)4096 * 3072;         // 4M  (total ~48MB)
    unsigned short* abf = xb;                                // alias: x dead after QKV GEMM

    detect_dtype<<<1, 256, 0, stream>>>((const unsigned short*)x, flag);

    convert_bf16<<<(4194304 + 255) / 256, 256, 0, stream>>>(x, xb, 4194304, flag);
    convtrans_k<<<dim3(16, 16, 4), 256, 0, stream>>>(Wq, Wk, Wv, Wo, WT, flag);
    convert_bias<<<16, 256, 0, stream>>>(bq, bk, bv, bo, b3, bob, flag);

    gemm_bias_relu<<<dim3(24, 32), 256, 0, stream>>>(xb, WT, b3, qkv, VtG, flag, 4096, 3072, 1024, 2);
    attn_kernel<<<dim3(16, 32), 256, 0, stream>>>(qkv, VtG, mk, abf);
    gemm_bias_relu<<<dim3(8, 32), 256, 0, stream>>>(abf, WoT, bob, d_out, VtG, flag, 4096, 1024, 1024, 1);
}

// Round 8
// 261.431 us; speedup vs baseline: 1.0988x; 1.0174x over previous
//
#include <hip/hip_runtime.h>
#include <stdint.h>

typedef __attribute__((ext_vector_type(8))) short short8;   // 8 bf16 (4 VGPRs)
typedef __attribute__((ext_vector_type(4))) float f32x4;    // MFMA acc
typedef __attribute__((ext_vector_type(4))) unsigned short ushort4_t;

#define MFMA16(a, b, c) __builtin_amdgcn_mfma_f32_16x16x32_bf16((a), (b), (c), 0, 0, 0)

__device__ __forceinline__ float b2f(unsigned short u) {
    union { unsigned u; float f; } c; c.u = ((unsigned)u) << 16; return c.f;
}
__device__ __forceinline__ unsigned short f2b(float f) {
    union { float f; unsigned u; } c; c.f = f;
    unsigned r = c.u + 0x7FFF + ((c.u >> 16) & 1);   // round-to-nearest-even
    return (unsigned short)(r >> 16);
}
__device__ __forceinline__ unsigned f_as_u(float f) {
    union { float f; unsigned u; } c; c.f = f; return c.u;
}

// async global->LDS, 16B per lane; LDS dest = wave-uniform base + lane*16.
__device__ __forceinline__ void g2lds16(const unsigned short* g, unsigned lds_byte_off) {
    __builtin_amdgcn_global_load_lds(
        (const __attribute__((address_space(1))) void*)(uintptr_t)g,
        (__attribute__((address_space(3))) void*)(uintptr_t)lds_byte_off,
        16, 0, 0);
}

// ---------------------------------------------------------------------------
// Dtype canary (proven): flag=1 => f32 inputs, 0 => bf16.
// ---------------------------------------------------------------------------
__global__ void detect_dtype(const unsigned short* __restrict__ x, int* __restrict__ flag) {
    __shared__ int cnt;
    if (threadIdx.x == 0) cnt = 0;
    __syncthreads();
    int insane = 0;
    #pragma unroll
    for (int j = 0; j < 4; ++j) {
        unsigned short u = x[threadIdx.x * 4 + j];
        int e = (u >> 7) & 0xFF;
        if ((e >= 1 && e <= 90) || e >= 165) insane++;
    }
    atomicAdd(&cnt, insane);
    __syncthreads();
    if (threadIdx.x == 0) *flag = (cnt > 128) ? 1 : 0;
}

// converts x only when f32 (flag=1); bf16 inputs are consumed in place by the
// QKV GEMM (pointer select on flag), so this early-exits. Deterministic per
// input -> graph-safe.
__global__ __launch_bounds__(256) void convert_x(const void* __restrict__ src,
                                                 unsigned short* __restrict__ dst,
                                                 int n, const int* __restrict__ flag) {
    if (!*flag) return;
    int i = blockIdx.x * 256 + threadIdx.x;
    if (i >= n) return;
    dst[i] = f2b(((const float*)src)[i]);
}

// ---------------------------------------------------------------------------
// Fused convert + transpose for 4 weights (z=0..3) + all biases (z=4).
// ---------------------------------------------------------------------------
__global__ __launch_bounds__(256) void convtrans_k(const void* __restrict__ s0, const void* __restrict__ s1,
                                                   const void* __restrict__ s2, const void* __restrict__ s3,
                                                   const void* __restrict__ b0, const void* __restrict__ b1,
                                                   const void* __restrict__ b2, const void* __restrict__ b3s,
                                                   unsigned short* __restrict__ dstBase,
                                                   unsigned short* __restrict__ dstB3,
                                                   unsigned short* __restrict__ dstBo,
                                                   const int* __restrict__ flag) {
    const int z = blockIdx.z;
    if (z == 4) {   // biases: 4 active blocks, 1024 elems each
        if (blockIdx.y != 0 || blockIdx.x >= 4) return;
        const int w = blockIdx.x;
        const void* src = (w == 0) ? b0 : (w == 1) ? b1 : (w == 2) ? b2 : b3s;
        #pragma unroll
        for (int j = 0; j < 4; ++j) {
            const int i = threadIdx.x * 4 + j;
            unsigned short v = (*flag) ? f2b(((const float*)src)[i]) : ((const unsigned short*)src)[i];
            if (w < 3) dstB3[w * 1024 + i] = v;
            else dstBo[i] = v;
        }
        return;
    }
    __shared__ __align__(16) unsigned short tile[64 * 72];
    const void* src = (z == 0) ? s0 : (z == 1) ? s1 : (z == 2) ? s2 : s3;
    unsigned short* dst = dstBase + (size_t)z * 1024 * 1024;
    const int tid = threadIdx.x;
    const int r0 = blockIdx.y * 64, c0 = blockIdx.x * 64;
    const int rb = tid >> 3, c = (tid & 7) * 8;
    if (*flag) {
        const float* s = (const float*)src;
        #pragma unroll
        for (int it = 0; it < 2; ++it) {
            int rr = it * 32 + rb;
            float4 f0 = *(const float4*)&s[(size_t)(r0 + rr) * 1024 + c0 + c];
            float4 f1 = *(const float4*)&s[(size_t)(r0 + rr) * 1024 + c0 + c + 4];
            unsigned short* t = &tile[rr * 72 + c];
            t[0] = f2b(f0.x); t[1] = f2b(f0.y); t[2] = f2b(f0.z); t[3] = f2b(f0.w);
            t[4] = f2b(f1.x); t[5] = f2b(f1.y); t[6] = f2b(f1.z); t[7] = f2b(f1.w);
        }
    } else {
        const unsigned short* s = (const unsigned short*)src;
        #pragma unroll
        for (int it = 0; it < 2; ++it) {
            int rr = it * 32 + rb;
            *(short8*)&tile[rr * 72 + c] = *(const short8*)&s[(size_t)(r0 + rr) * 1024 + c0 + c];
        }
    }
    __syncthreads();
    #pragma unroll
    for (int it = 0; it < 2; ++it) {
        int n = it * 32 + rb, k8 = c;
        union { short8 s; unsigned short u[8]; } tmp;
        #pragma unroll
        for (int j = 0; j < 8; ++j) tmp.u[j] = tile[(k8 + j) * 72 + n];
        *(short8*)&dst[(size_t)(c0 + n) * 1024 + r0 + k8] = tmp.s;
    }
}

// ---------------------------------------------------------------------------
// C = relu(A[M,K] @ BT[N,K]^T + bias[N]); m97 staging.
// Araw: if non-null and *flag==0, used instead of A (raw bf16 input).
// mode 0: bf16 store. mode 1: final (f32/bf16 per flag).
// mode 2: QKV — V columns (n0>=2048) stored transposed into VtG[bh][dk][seq].
// ---------------------------------------------------------------------------
__global__ __launch_bounds__(256) void gemm_bias_relu(const unsigned short* __restrict__ A,
                                                      const void* __restrict__ Araw,
                                                      const unsigned short* __restrict__ BT,
                                                      const unsigned short* __restrict__ bias,
                                                      void* __restrict__ C,
                                                      unsigned short* __restrict__ VtG,
                                                      const int* __restrict__ flag,
                                                      int M, int N, int K, int mode) {
    __shared__ __align__(16) unsigned short As[128 * 32];
    __shared__ __align__(16) unsigned short Bs[128 * 32];
    const int tid = threadIdx.x;
    const int wave = tid >> 6, lane = tid & 63;
    const int quad = lane >> 4, l16 = lane & 15;
    const int wm = wave >> 1, wn = wave & 1;
    const int m0 = blockIdx.y * 128, n0 = blockIdx.x * 128;

    const unsigned short* Ause = (Araw != nullptr && *flag == 0) ? (const unsigned short*)Araw : A;

    f32x4 acc[4][4];
    #pragma unroll
    for (int i = 0; i < 4; i++)
        #pragma unroll
        for (int j = 0; j < 4; j++) acc[i][j] = (f32x4){0.f, 0.f, 0.f, 0.f};

    const int srow = wave * 32 + (lane >> 2);
    const int sc8  = (lane & 3) * 8;
    const unsigned short* gA0 = Ause + (size_t)(m0 + srow) * K + sc8;
    const unsigned short* gA1 = gA0 + (size_t)16 * K;
    const unsigned short* gB0 = BT + (size_t)(n0 + srow) * K + sc8;
    const unsigned short* gB1 = gB0 + (size_t)16 * K;
    const unsigned ldsA = (unsigned)(uintptr_t)&As[0] + wave * 2048;
    const unsigned ldsB = (unsigned)(uintptr_t)&Bs[0] + wave * 2048;

    for (int k0 = 0; k0 < K; k0 += 32) {
        __syncthreads();
        g2lds16(gA0 + k0, ldsA);
        g2lds16(gA1 + k0, ldsA + 1024);
        g2lds16(gB0 + k0, ldsB);
        g2lds16(gB1 + k0, ldsB + 1024);
        __syncthreads();
        short8 af[4], bf[4];
        #pragma unroll
        for (int i = 0; i < 4; i++) af[i] = *(const short8*)&As[(wm * 64 + i * 16 + l16) * 32 + quad * 8];
        #pragma unroll
        for (int j = 0; j < 4; j++) bf[j] = *(const short8*)&Bs[(wn * 64 + j * 16 + l16) * 32 + quad * 8];
        #pragma unroll
        for (int i = 0; i < 4; i++)
            #pragma unroll
            for (int j = 0; j < 4; j++)
                acc[i][j] = MFMA16(af[i], bf[j], acc[i][j]);
    }

    if (mode == 2 && n0 >= 2048) {
        #pragma unroll
        for (int j = 0; j < 4; j++) {
            const int col = n0 + wn * 64 + j * 16 + l16;       // 2048..3071
            const int h  = (col - 2048) >> 6;
            const int dk = (col - 2048) & 63;
            const float bj = b2f(bias[col]);
            #pragma unroll
            for (int i = 0; i < 4; i++) {
                const int rowb = m0 + wm * 64 + i * 16 + quad * 4;
                const int bb = rowb >> 11;
                const int s0 = rowb & 2047;
                ushort4_t w;
                #pragma unroll
                for (int r = 0; r < 4; r++) {
                    float v = acc[i][j][r] + bj;
                    v = v > 0.f ? v : 0.f;
                    w[r] = f2b(v);
                }
                *(ushort4_t*)&VtG[(size_t)((bb * 16 + h) * 64 + dk) * 2048 + s0] = w;
            }
        }
    } else {
        const int f32out = (mode == 1) && (*flag != 0);
        #pragma unroll
        for (int j = 0; j < 4; j++) {
            const int col = n0 + wn * 64 + j * 16 + l16;
            const float bj = b2f(bias[col]);
            #pragma unroll
            for (int i = 0; i < 4; i++) {
                const int rowb = m0 + wm * 64 + i * 16 + quad * 4;
                #pragma unroll
                for (int r = 0; r < 4; r++) {
                    float v = acc[i][j][r] + bj;
                    v = v > 0.f ? v : 0.f;
                    if (f32out) ((float*)C)[(size_t)(rowb + r) * N + col] = v;
                    else ((unsigned short*)C)[(size_t)(rowb + r) * N + col] = f2b(v);
                }
            }
        }
    }
}

// ---------------------------------------------------------------------------
// Attention: no-max softmax + deferred row-sum; mask folded into the exp2
// SCALE (masked => scale 0 => exp2(0)=1 exactly, staying in the denominator
// like the reference's exp(1e-9)). 4 cndmask/tile instead of 64; raw-f32
// l-sum (drops trunc-consistency AND). Round-7 structure otherwise.
// ---------------------------------------------------------------------------
__global__ __launch_bounds__(256) void attn_kernel(const unsigned short* __restrict__ qkv,
                                                   const unsigned short* __restrict__ VtG,
                                                   const int* __restrict__ mask,
                                                   unsigned short* __restrict__ out) {
    __shared__ __align__(16) unsigned short Ks[64 * 72];       // [key][dk]
    __shared__ __align__(16) unsigned short Vs[64 * 72];       // [dk][key]
    __shared__ __align__(16) unsigned short Ps[4][2][16 * 68]; // per-wave, per-frag P
    __shared__ unsigned char maskB[2048];

    const int qt = blockIdx.x, bh = blockIdx.y;
    const int b = bh >> 4, h = bh & 15;
    const int tid = threadIdx.x, wave = tid >> 6, lane = tid & 63;
    const int quad = lane >> 4, l16 = lane & 15;

    for (int i = tid; i < 2048; i += 256) maskB[i] = (unsigned char)(mask[b * 2048 + i] != 0);

    const int qrowA = qt * 128 + wave * 16 + l16;
    const unsigned short* qpA = qkv + (size_t)(b * 2048 + qrowA) * 3072 + h * 64;
    const unsigned short* qpB = qpA + (size_t)64 * 3072;
    const short8 qa0 = *(const short8*)(qpA + quad * 8);
    const short8 qa1 = *(const short8*)(qpA + 32 + quad * 8);
    const short8 qb0 = *(const short8*)(qpB + quad * 8);
    const short8 qb1 = *(const short8*)(qpB + 32 + quad * 8);

    f32x4 oA[4], oB[4];
    float lA[4], lB[4];
    #pragma unroll
    for (int n = 0; n < 4; n++) { oA[n] = (f32x4){0.f,0.f,0.f,0.f}; oB[n] = (f32x4){0.f,0.f,0.f,0.f}; }
    #pragma unroll
    for (int r = 0; r < 4; r++) { lA[r] = 0.f; lB[r] = 0.f; }

    const int srow = tid >> 2;          // 0..63
    const int scol = (tid & 3) * 16;    // 0,16,32,48
    const unsigned short* kg = qkv + (size_t)(b * 2048 + srow) * 3072 + 1024 + h * 64 + scol;
    const unsigned short* vg = VtG + (size_t)(bh * 64 + srow) * 2048 + scol;
    const size_t kstep = (size_t)64 * 3072;
    unsigned short* wK = &Ks[srow * 72 + scol];
    unsigned short* wV = &Vs[srow * 72 + scol];
    unsigned short* PwA = Ps[wave][0];
    unsigned short* PwB = Ps[wave][1];

    const float SCL = 0.125f * 1.44269504f;   // dk^-0.5 folded with log2(e)

    for (int kt = 0; kt < 32; ++kt) {
        __syncthreads();
        *(short8*)wK       = *(const short8*)(kg + kt * kstep);
        *(short8*)(wK + 8) = *(const short8*)(kg + kt * kstep + 8);
        *(short8*)wV       = *(const short8*)(vg + kt * 64);
        *(short8*)(wV + 8) = *(const short8*)(vg + kt * 64 + 8);
        __syncthreads();

        // per-subtile scale: 0 for masked keys (exp2(0)=1), SCL otherwise
        float sclv[4];
        #pragma unroll
        for (int t = 0; t < 4; ++t)
            sclv[t] = maskB[kt * 64 + t * 16 + l16] ? 0.f : SCL;

        // QK^T for both frags (K fragments shared)
        f32x4 sA[4], sB[4];
        #pragma unroll
        for (int t = 0; t < 4; ++t) {
            const short8 kb0 = *(const short8*)&Ks[(t * 16 + l16) * 72 + quad * 8];
            const short8 kb1 = *(const short8*)&Ks[(t * 16 + l16) * 72 + 32 + quad * 8];
            f32x4 z = (f32x4){0.f, 0.f, 0.f, 0.f};
            sA[t] = MFMA16(qa1, kb1, MFMA16(qa0, kb0, z));
            sB[t] = MFMA16(qb1, kb1, MFMA16(qb0, kb0, z));
        }

        // cache V fragments once; reused by both frags
        short8 vb[4][2];
        #pragma unroll
        for (int n = 0; n < 4; ++n) {
            vb[n][0] = *(const short8*)&Vs[(n * 16 + l16) * 72 + quad * 8];
            vb[n][1] = *(const short8*)&Vs[(n * 16 + l16) * 72 + 32 + quad * 8];
        }

        #pragma unroll
        for (int t = 0; t < 4; ++t) {
            #pragma unroll
            for (int r = 0; r < 4; ++r) {
                const float p = exp2f(sA[t][r] * sclv[t]);
                lA[r] += p;
                PwA[(quad * 4 + r) * 68 + t * 16 + l16] = (unsigned short)(f_as_u(p) >> 16);
            }
        }
        #pragma unroll
        for (int t = 0; t < 4; ++t) {
            #pragma unroll
            for (int r = 0; r < 4; ++r) {
                const float p = exp2f(sB[t][r] * sclv[t]);
                lB[r] += p;
                PwB[(quad * 4 + r) * 68 + t * 16 + l16] = (unsigned short)(f_as_u(p) >> 16);
            }
        }
        __builtin_amdgcn_s_waitcnt(0xC07F);   // single lgkmcnt(0) drain for both P buffers

        {
            const short8 paA0 = *(const short8*)&PwA[l16 * 68 + quad * 8];
            const short8 paA1 = *(const short8*)&PwA[l16 * 68 + 32 + quad * 8];
            const short8 paB0 = *(const short8*)&PwB[l16 * 68 + quad * 8];
            const short8 paB1 = *(const short8*)&PwB[l16 * 68 + 32 + quad * 8];
            #pragma unroll
            for (int n = 0; n < 4; ++n) {
                oA[n] = MFMA16(paA0, vb[n][0], oA[n]);
                oA[n] = MFMA16(paA1, vb[n][1], oA[n]);
                oB[n] = MFMA16(paB0, vb[n][0], oB[n]);
                oB[n] = MFMA16(paB1, vb[n][1], oB[n]);
            }
        }
    }

    #pragma unroll
    for (int d = 1; d < 16; d <<= 1)
        #pragma unroll
        for (int r = 0; r < 4; r++) {
            lA[r] += __shfl_xor(lA[r], d, 16);
            lB[r] += __shfl_xor(lB[r], d, 16);
        }
    #pragma unroll
    for (int r = 0; r < 4; r++) { lA[r] = 1.0f / lA[r]; lB[r] = 1.0f / lB[r]; }
    #pragma unroll
    for (int n = 0; n < 4; n++)
        #pragma unroll
        for (int r = 0; r < 4; r++) {
            const int row = qt * 128 + wave * 16 + quad * 4 + r;
            out[(size_t)(b * 2048 + row) * 1024 + h * 64 + n * 16 + l16] = f2b(oA[n][r] * lA[r]);
            out[(size_t)(b * 2048 + row + 64) * 1024 + h * 64 + n * 16 + l16] = f2b(oB[n][r] * lB[r]);
        }
}

// ---------------------------------------------------------------------------
extern "C" void kernel_launch(void* const* d_in, const int* in_sizes, int n_in,
                              void* d_out, int out_size, void* d_ws, size_t ws_size,
                              hipStream_t stream) {
    const void* x  = d_in[0];
    const int*  mk = (const int*)d_in[1];
    const void* Wq = d_in[2]; const void* bq = d_in[3];
    const void* Wk = d_in[4]; const void* bk = d_in[5];
    const void* Wv = d_in[6]; const void* bv = d_in[7];
    const void* Wo = d_in[8]; const void* bo = d_in[9];

    char* wsb = (char*)d_ws;
    int* flag = (int*)wsb;                                   // 64B header
    unsigned short* W0 = (unsigned short*)(wsb + 64);

    const size_t M1 = 1024u * 1024u;
    const size_t M4 = 4096u * 1024u;
    unsigned short* xb  = W0;                                // 4M elems (reused as abf)
    unsigned short* WT  = xb + M4;                           // 3M: Wq^T|Wk^T|Wv^T
    unsigned short* WoT = WT + 3 * M1;                       // 1M (contiguous after WT)
    unsigned short* b3  = WoT + M1;                          // 3072 (pad 4096)
    unsigned short* bob = b3 + 4096;                         // 1024
    unsigned short* qkv = bob + 1024;                        // 12M (V third unused)
    unsigned short* VtG = qkv + (size_t)4096 * 3072;         // 4M  (total ~48MB)
    unsigned short* abf = xb;                                // alias: x dead after QKV GEMM

    detect_dtype<<<1, 256, 0, stream>>>((const unsigned short*)x, flag);

    convert_x<<<(4194304 + 255) / 256, 256, 0, stream>>>(x, xb, 4194304, flag);
    convtrans_k<<<dim3(16, 16, 5), 256, 0, stream>>>(Wq, Wk, Wv, Wo, bq, bk, bv, bo,
                                                     WT, b3, bob, flag);

    gemm_bias_relu<<<dim3(24, 32), 256, 0, stream>>>(xb, x, WT, b3, qkv, VtG, flag, 4096, 3072, 1024, 2);
    attn_kernel<<<dim3(16, 32), 256, 0, stream>>>(qkv, VtG, mk, abf);
    gemm_bias_relu<<<dim3(8, 32), 256, 0, stream>>>(abf, nullptr, WoT, bob, d_out, VtG, flag, 4096, 1024, 1024, 1);
}

// Round 9
// 243.438 us; speedup vs baseline: 1.1800x; 1.0739x over previous
//
#include <hip/hip_runtime.h>
#include <stdint.h>

typedef __attribute__((ext_vector_type(8))) short short8;   // 8 bf16 (4 VGPRs)
typedef __attribute__((ext_vector_type(4))) short short4b;  // 4 bf16 (2 VGPRs)
typedef __attribute__((ext_vector_type(4))) float f32x4;    // MFMA acc
typedef __attribute__((ext_vector_type(4))) unsigned short ushort4_t;

#define MFMA16(a, b, c) __builtin_amdgcn_mfma_f32_16x16x32_bf16((a), (b), (c), 0, 0, 0)

#if __has_builtin(__builtin_amdgcn_mfma_f32_16x16x16bf16_1k)
  #define HAVE_MFMA16X16X16 1
  #define MFMA16K16(a, b, c) __builtin_amdgcn_mfma_f32_16x16x16bf16_1k((a), (b), (c), 0, 0, 0)
#elif __has_builtin(__builtin_amdgcn_mfma_f32_16x16x16_bf16)
  #define HAVE_MFMA16X16X16 1
  #define MFMA16K16(a, b, c) __builtin_amdgcn_mfma_f32_16x16x16_bf16((a), (b), (c), 0, 0, 0)
#else
  #define HAVE_MFMA16X16X16 0
#endif

__device__ __forceinline__ float b2f(unsigned short u) {
    union { unsigned u; float f; } c; c.u = ((unsigned)u) << 16; return c.f;
}
__device__ __forceinline__ unsigned short f2b(float f) {
    union { float f; unsigned u; } c; c.f = f;
    unsigned r = c.u + 0x7FFF + ((c.u >> 16) & 1);   // round-to-nearest-even
    return (unsigned short)(r >> 16);
}
__device__ __forceinline__ unsigned f_as_u(float f) {
    union { float f; unsigned u; } c; c.f = f; return c.u;
}

// async global->LDS, 16B per lane; LDS dest = wave-uniform base + lane*16.
__device__ __forceinline__ void g2lds16(const unsigned short* g, unsigned lds_byte_off) {
    __builtin_amdgcn_global_load_lds(
        (const __attribute__((address_space(1))) void*)(uintptr_t)g,
        (__attribute__((address_space(3))) void*)(uintptr_t)lds_byte_off,
        16, 0, 0);
}

// ---------------------------------------------------------------------------
// Dtype canary (proven): flag=1 => f32 inputs, 0 => bf16.
// ---------------------------------------------------------------------------
__global__ void detect_dtype(const unsigned short* __restrict__ x, int* __restrict__ flag) {
    __shared__ int cnt;
    if (threadIdx.x == 0) cnt = 0;
    __syncthreads();
    int insane = 0;
    #pragma unroll
    for (int j = 0; j < 4; ++j) {
        unsigned short u = x[threadIdx.x * 4 + j];
        int e = (u >> 7) & 0xFF;
        if ((e >= 1 && e <= 90) || e >= 165) insane++;
    }
    atomicAdd(&cnt, insane);
    __syncthreads();
    if (threadIdx.x == 0) *flag = (cnt > 128) ? 1 : 0;
}

__global__ __launch_bounds__(256) void convert_x(const void* __restrict__ src,
                                                 unsigned short* __restrict__ dst,
                                                 int n, const int* __restrict__ flag) {
    if (!*flag) return;
    int i = blockIdx.x * 256 + threadIdx.x;
    if (i >= n) return;
    dst[i] = f2b(((const float*)src)[i]);
}

// ---------------------------------------------------------------------------
// Fused convert + transpose for 4 weights (z=0..3) + all biases (z=4).
// ---------------------------------------------------------------------------
__global__ __launch_bounds__(256) void convtrans_k(const void* __restrict__ s0, const void* __restrict__ s1,
                                                   const void* __restrict__ s2, const void* __restrict__ s3,
                                                   const void* __restrict__ b0, const void* __restrict__ b1,
                                                   const void* __restrict__ b2, const void* __restrict__ b3s,
                                                   unsigned short* __restrict__ dstBase,
                                                   unsigned short* __restrict__ dstB3,
                                                   unsigned short* __restrict__ dstBo,
                                                   const int* __restrict__ flag) {
    const int z = blockIdx.z;
    if (z == 4) {
        if (blockIdx.y != 0 || blockIdx.x >= 4) return;
        const int w = blockIdx.x;
        const void* src = (w == 0) ? b0 : (w == 1) ? b1 : (w == 2) ? b2 : b3s;
        #pragma unroll
        for (int j = 0; j < 4; ++j) {
            const int i = threadIdx.x * 4 + j;
            unsigned short v = (*flag) ? f2b(((const float*)src)[i]) : ((const unsigned short*)src)[i];
            if (w < 3) dstB3[w * 1024 + i] = v;
            else dstBo[i] = v;
        }
        return;
    }
    __shared__ __align__(16) unsigned short tile[64 * 72];
    const void* src = (z == 0) ? s0 : (z == 1) ? s1 : (z == 2) ? s2 : s3;
    unsigned short* dst = dstBase + (size_t)z * 1024 * 1024;
    const int tid = threadIdx.x;
    const int r0 = blockIdx.y * 64, c0 = blockIdx.x * 64;
    const int rb = tid >> 3, c = (tid & 7) * 8;
    if (*flag) {
        const float* s = (const float*)src;
        #pragma unroll
        for (int it = 0; it < 2; ++it) {
            int rr = it * 32 + rb;
            float4 f0 = *(const float4*)&s[(size_t)(r0 + rr) * 1024 + c0 + c];
            float4 f1 = *(const float4*)&s[(size_t)(r0 + rr) * 1024 + c0 + c + 4];
            unsigned short* t = &tile[rr * 72 + c];
            t[0] = f2b(f0.x); t[1] = f2b(f0.y); t[2] = f2b(f0.z); t[3] = f2b(f0.w);
            t[4] = f2b(f1.x); t[5] = f2b(f1.y); t[6] = f2b(f1.z); t[7] = f2b(f1.w);
        }
    } else {
        const unsigned short* s = (const unsigned short*)src;
        #pragma unroll
        for (int it = 0; it < 2; ++it) {
            int rr = it * 32 + rb;
            *(short8*)&tile[rr * 72 + c] = *(const short8*)&s[(size_t)(r0 + rr) * 1024 + c0 + c];
        }
    }
    __syncthreads();
    #pragma unroll
    for (int it = 0; it < 2; ++it) {
        int n = it * 32 + rb, k8 = c;
        union { short8 s; unsigned short u[8]; } tmp;
        #pragma unroll
        for (int j = 0; j < 8; ++j) tmp.u[j] = tile[(k8 + j) * 72 + n];
        *(short8*)&dst[(size_t)(c0 + n) * 1024 + r0 + k8] = tmp.s;
    }
}

// ---------------------------------------------------------------------------
// C = relu(A[M,K] @ BT[N,K]^T + bias[N]); m97 staging.
// mode 0: bf16. mode 1: final (f32/bf16 per flag). mode 2: QKV w/ V transposed.
// ---------------------------------------------------------------------------
__global__ __launch_bounds__(256) void gemm_bias_relu(const unsigned short* __restrict__ A,
                                                      const void* __restrict__ Araw,
                                                      const unsigned short* __restrict__ BT,
                                                      const unsigned short* __restrict__ bias,
                                                      void* __restrict__ C,
                                                      unsigned short* __restrict__ VtG,
                                                      const int* __restrict__ flag,
                                                      int M, int N, int K, int mode) {
    __shared__ __align__(16) unsigned short As[128 * 32];
    __shared__ __align__(16) unsigned short Bs[128 * 32];
    const int tid = threadIdx.x;
    const int wave = tid >> 6, lane = tid & 63;
    const int quad = lane >> 4, l16 = lane & 15;
    const int wm = wave >> 1, wn = wave & 1;
    const int m0 = blockIdx.y * 128, n0 = blockIdx.x * 128;

    const unsigned short* Ause = (Araw != nullptr && *flag == 0) ? (const unsigned short*)Araw : A;

    f32x4 acc[4][4];
    #pragma unroll
    for (int i = 0; i < 4; i++)
        #pragma unroll
        for (int j = 0; j < 4; j++) acc[i][j] = (f32x4){0.f, 0.f, 0.f, 0.f};

    const int srow = wave * 32 + (lane >> 2);
    const int sc8  = (lane & 3) * 8;
    const unsigned short* gA0 = Ause + (size_t)(m0 + srow) * K + sc8;
    const unsigned short* gA1 = gA0 + (size_t)16 * K;
    const unsigned short* gB0 = BT + (size_t)(n0 + srow) * K + sc8;
    const unsigned short* gB1 = gB0 + (size_t)16 * K;
    const unsigned ldsA = (unsigned)(uintptr_t)&As[0] + wave * 2048;
    const unsigned ldsB = (unsigned)(uintptr_t)&Bs[0] + wave * 2048;

    for (int k0 = 0; k0 < K; k0 += 32) {
        __syncthreads();
        g2lds16(gA0 + k0, ldsA);
        g2lds16(gA1 + k0, ldsA + 1024);
        g2lds16(gB0 + k0, ldsB);
        g2lds16(gB1 + k0, ldsB + 1024);
        __syncthreads();
        short8 af[4], bf[4];
        #pragma unroll
        for (int i = 0; i < 4; i++) af[i] = *(const short8*)&As[(wm * 64 + i * 16 + l16) * 32 + quad * 8];
        #pragma unroll
        for (int j = 0; j < 4; j++) bf[j] = *(const short8*)&Bs[(wn * 64 + j * 16 + l16) * 32 + quad * 8];
        #pragma unroll
        for (int i = 0; i < 4; i++)
            #pragma unroll
            for (int j = 0; j < 4; j++)
                acc[i][j] = MFMA16(af[i], bf[j], acc[i][j]);
    }

    if (mode == 2 && n0 >= 2048) {
        #pragma unroll
        for (int j = 0; j < 4; j++) {
            const int col = n0 + wn * 64 + j * 16 + l16;
            const int h  = (col - 2048) >> 6;
            const int dk = (col - 2048) & 63;
            const float bj = b2f(bias[col]);
            #pragma unroll
            for (int i = 0; i < 4; i++) {
                const int rowb = m0 + wm * 64 + i * 16 + quad * 4;
                const int bb = rowb >> 11;
                const int s0 = rowb & 2047;
                ushort4_t w;
                #pragma unroll
                for (int r = 0; r < 4; r++) {
                    float v = acc[i][j][r] + bj;
                    v = v > 0.f ? v : 0.f;
                    w[r] = f2b(v);
                }
                *(ushort4_t*)&VtG[(size_t)((bb * 16 + h) * 64 + dk) * 2048 + s0] = w;
            }
        }
    } else {
        const int f32out = (mode == 1) && (*flag != 0);
        #pragma unroll
        for (int j = 0; j < 4; j++) {
            const int col = n0 + wn * 64 + j * 16 + l16;
            const float bj = b2f(bias[col]);
            #pragma unroll
            for (int i = 0; i < 4; i++) {
                const int rowb = m0 + wm * 64 + i * 16 + quad * 4;
                #pragma unroll
                for (int r = 0; r < 4; r++) {
                    float v = acc[i][j][r] + bj;
                    v = v > 0.f ? v : 0.f;
                    if (f32out) ((float*)C)[(size_t)(rowb + r) * N + col] = v;
                    else ((unsigned short*)C)[(size_t)(rowb + r) * N + col] = f2b(v);
                }
            }
        }
    }
}

#if HAVE_MFMA16X16X16
// ---------------------------------------------------------------------------
// Attention v2: QK^T computed TRANSPOSED (A=K, B=Q => S^T), so each lane's
// accumulator IS the A-operand of a 16x16x16 PV MFMA (P[q=l16][k=quad*4+r]).
// exp in registers, pack, feed PV directly: NO P LDS round trip, no drain.
// Mask folded as f32 scale array in LDS (b128 per subtile). l-sum per lane
// (same q), reduced across quads once; 4-shuffle transpose aligns it with
// the C-layout rows for the final scale.
// ---------------------------------------------------------------------------
__global__ __launch_bounds__(256) void attn_kernel(const unsigned short* __restrict__ qkv,
                                                   const unsigned short* __restrict__ VtG,
                                                   const int* __restrict__ mask,
                                                   unsigned short* __restrict__ out) {
    __shared__ __align__(16) unsigned short Ks[64 * 72];    // [key][dk]
    __shared__ __align__(16) unsigned short Vs[64 * 72];    // [dk][key]
    __shared__ __align__(16) float maskF[2048];             // 0 (masked) or SCL

    const int qt = blockIdx.x, bh = blockIdx.y;
    const int b = bh >> 4, h = bh & 15;
    const int tid = threadIdx.x, wave = tid >> 6, lane = tid & 63;
    const int quad = lane >> 4, l16 = lane & 15;

    const float SCL = 0.125f * 1.44269504f;   // dk^-0.5 folded with log2(e)
    for (int i = tid; i < 2048; i += 256) maskF[i] = mask[b * 2048 + i] ? 0.f : SCL;

    const int qrowA = qt * 128 + wave * 16 + l16;
    const unsigned short* qpA = qkv + (size_t)(b * 2048 + qrowA) * 3072 + h * 64;
    const unsigned short* qpB = qpA + (size_t)64 * 3072;
    const short8 qa0 = *(const short8*)(qpA + quad * 8);
    const short8 qa1 = *(const short8*)(qpA + 32 + quad * 8);
    const short8 qb0 = *(const short8*)(qpB + quad * 8);
    const short8 qb1 = *(const short8*)(qpB + 32 + quad * 8);

    f32x4 oA[4], oB[4];
    float lqA = 0.f, lqB = 0.f;       // denominator for q=l16 (partial: this lane's keys)
    #pragma unroll
    for (int n = 0; n < 4; n++) { oA[n] = (f32x4){0.f,0.f,0.f,0.f}; oB[n] = (f32x4){0.f,0.f,0.f,0.f}; }

    const int srow = tid >> 2;          // 0..63
    const int scol = (tid & 3) * 16;    // 0,16,32,48
    const unsigned short* kg = qkv + (size_t)(b * 2048 + srow) * 3072 + 1024 + h * 64 + scol;
    const unsigned short* vg = VtG + (size_t)(bh * 64 + srow) * 2048 + scol;
    const size_t kstep = (size_t)64 * 3072;
    unsigned short* wK = &Ks[srow * 72 + scol];
    unsigned short* wV = &Vs[srow * 72 + scol];

    for (int kt = 0; kt < 32; ++kt) {
        __syncthreads();
        *(short8*)wK       = *(const short8*)(kg + kt * kstep);
        *(short8*)(wK + 8) = *(const short8*)(kg + kt * kstep + 8);
        *(short8*)wV       = *(const short8*)(vg + kt * 64);
        *(short8*)(wV + 8) = *(const short8*)(vg + kt * 64 + 8);
        __syncthreads();

        // S^T = K·Q^T per 16-key subtile: row = key = quad*4+r, col = q = l16
        f32x4 sA[4], sB[4];
        #pragma unroll
        for (int t = 0; t < 4; ++t) {
            const short8 kb0 = *(const short8*)&Ks[(t * 16 + l16) * 72 + quad * 8];
            const short8 kb1 = *(const short8*)&Ks[(t * 16 + l16) * 72 + 32 + quad * 8];
            f32x4 z = (f32x4){0.f, 0.f, 0.f, 0.f};
            sA[t] = MFMA16(kb1, qa1, MFMA16(kb0, qa0, z));
            sB[t] = MFMA16(kb1, qb1, MFMA16(kb0, qb0, z));
        }

        // V B-frags (16x16x16): keys t*16+quad*4..+3 for dk-block n — b64 reads
        short4b vb[4][4];
        #pragma unroll
        for (int t = 0; t < 4; ++t)
            #pragma unroll
            for (int n = 0; n < 4; ++n)
                vb[t][n] = *(const short4b*)&Vs[(n * 16 + l16) * 72 + t * 16 + quad * 4];

        #pragma unroll
        for (int t = 0; t < 4; ++t) {
            const f32x4 scl = *(const f32x4*)&maskF[kt * 64 + t * 16 + quad * 4];
            float pA[4], pB[4];
            #pragma unroll
            for (int r = 0; r < 4; ++r) {
                pA[r] = exp2f(sA[t][r] * scl[r]);
                pB[r] = exp2f(sB[t][r] * scl[r]);
                lqA += pA[r];
                lqB += pB[r];
            }
            // pack this lane's 4 p-values = the 16x16x16 A-frag (truncating bf16)
            union { unsigned u[2]; short4b s; } fa, fb;
            fa.u[0] = (f_as_u(pA[1]) & 0xFFFF0000u) | (f_as_u(pA[0]) >> 16);
            fa.u[1] = (f_as_u(pA[3]) & 0xFFFF0000u) | (f_as_u(pA[2]) >> 16);
            fb.u[0] = (f_as_u(pB[1]) & 0xFFFF0000u) | (f_as_u(pB[0]) >> 16);
            fb.u[1] = (f_as_u(pB[3]) & 0xFFFF0000u) | (f_as_u(pB[2]) >> 16);
            #pragma unroll
            for (int n = 0; n < 4; ++n) {
                oA[n] = MFMA16K16(fa.s, vb[t][n], oA[n]);
                oB[n] = MFMA16K16(fb.s, vb[t][n], oB[n]);
            }
        }
    }

    // complete denominators: sum across the 4 quads (all lanes with same l16)
    lqA += __shfl_xor(lqA, 16); lqA += __shfl_xor(lqA, 32);
    lqB += __shfl_xor(lqB, 16); lqB += __shfl_xor(lqB, 32);
    // O rows are q = quad*4+r; fetch matching denominators via intra-16 shuffle
    float invA[4], invB[4];
    #pragma unroll
    for (int r = 0; r < 4; ++r) {
        invA[r] = 1.0f / __shfl(lqA, quad * 4 + r, 16);
        invB[r] = 1.0f / __shfl(lqB, quad * 4 + r, 16);
    }
    #pragma unroll
    for (int n = 0; n < 4; n++)
        #pragma unroll
        for (int r = 0; r < 4; r++) {
            const int row = qt * 128 + wave * 16 + quad * 4 + r;
            out[(size_t)(b * 2048 + row) * 1024 + h * 64 + n * 16 + l16] = f2b(oA[n][r] * invA[r]);
            out[(size_t)(b * 2048 + row + 64) * 1024 + h * 64 + n * 16 + l16] = f2b(oB[n][r] * invB[r]);
        }
}
#else
// fallback: round-8 proven kernel (P via LDS round trip)
__global__ __launch_bounds__(256) void attn_kernel(const unsigned short* __restrict__ qkv,
                                                   const unsigned short* __restrict__ VtG,
                                                   const int* __restrict__ mask,
                                                   unsigned short* __restrict__ out) {
    __shared__ __align__(16) unsigned short Ks[64 * 72];
    __shared__ __align__(16) unsigned short Vs[64 * 72];
    __shared__ __align__(16) unsigned short Ps[4][2][16 * 68];
    __shared__ unsigned char maskB[2048];

    const int qt = blockIdx.x, bh = blockIdx.y;
    const int b = bh >> 4, h = bh & 15;
    const int tid = threadIdx.x, wave = tid >> 6, lane = tid & 63;
    const int quad = lane >> 4, l16 = lane & 15;

    for (int i = tid; i < 2048; i += 256) maskB[i] = (unsigned char)(mask[b * 2048 + i] != 0);

    const int qrowA = qt * 128 + wave * 16 + l16;
    const unsigned short* qpA = qkv + (size_t)(b * 2048 + qrowA) * 3072 + h * 64;
    const unsigned short* qpB = qpA + (size_t)64 * 3072;
    const short8 qa0 = *(const short8*)(qpA + quad * 8);
    const short8 qa1 = *(const short8*)(qpA + 32 + quad * 8);
    const short8 qb0 = *(const short8*)(qpB + quad * 8);
    const short8 qb1 = *(const short8*)(qpB + 32 + quad * 8);

    f32x4 oA[4], oB[4];
    float lA[4], lB[4];
    #pragma unroll
    for (int n = 0; n < 4; n++) { oA[n] = (f32x4){0.f,0.f,0.f,0.f}; oB[n] = (f32x4){0.f,0.f,0.f,0.f}; }
    #pragma unroll
    for (int r = 0; r < 4; r++) { lA[r] = 0.f; lB[r] = 0.f; }

    const int srow = tid >> 2;
    const int scol = (tid & 3) * 16;
    const unsigned short* kg = qkv + (size_t)(b * 2048 + srow) * 3072 + 1024 + h * 64 + scol;
    const unsigned short* vg = VtG + (size_t)(bh * 64 + srow) * 2048 + scol;
    const size_t kstep = (size_t)64 * 3072;
    unsigned short* wK = &Ks[srow * 72 + scol];
    unsigned short* wV = &Vs[srow * 72 + scol];
    unsigned short* PwA = Ps[wave][0];
    unsigned short* PwB = Ps[wave][1];

    const float SCL = 0.125f * 1.44269504f;

    for (int kt = 0; kt < 32; ++kt) {
        __syncthreads();
        *(short8*)wK       = *(const short8*)(kg + kt * kstep);
        *(short8*)(wK + 8) = *(const short8*)(kg + kt * kstep + 8);
        *(short8*)wV       = *(const short8*)(vg + kt * 64);
        *(short8*)(wV + 8) = *(const short8*)(vg + kt * 64 + 8);
        __syncthreads();

        float sclv[4];
        #pragma unroll
        for (int t = 0; t < 4; ++t)
            sclv[t] = maskB[kt * 64 + t * 16 + l16] ? 0.f : SCL;

        f32x4 sA[4], sB[4];
        #pragma unroll
        for (int t = 0; t < 4; ++t) {
            const short8 kb0 = *(const short8*)&Ks[(t * 16 + l16) * 72 + quad * 8];
            const short8 kb1 = *(const short8*)&Ks[(t * 16 + l16) * 72 + 32 + quad * 8];
            f32x4 z = (f32x4){0.f, 0.f, 0.f, 0.f};
            sA[t] = MFMA16(qa1, kb1, MFMA16(qa0, kb0, z));
            sB[t] = MFMA16(qb1, kb1, MFMA16(qb0, kb0, z));
        }

        short8 vbf[4][2];
        #pragma unroll
        for (int n = 0; n < 4; ++n) {
            vbf[n][0] = *(const short8*)&Vs[(n * 16 + l16) * 72 + quad * 8];
            vbf[n][1] = *(const short8*)&Vs[(n * 16 + l16) * 72 + 32 + quad * 8];
        }

        #pragma unroll
        for (int t = 0; t < 4; ++t)
            #pragma unroll
            for (int r = 0; r < 4; ++r) {
                const float p = exp2f(sA[t][r] * sclv[t]);
                lA[r] += p;
                PwA[(quad * 4 + r) * 68 + t * 16 + l16] = (unsigned short)(f_as_u(p) >> 16);
            }
        #pragma unroll
        for (int t = 0; t < 4; ++t)
            #pragma unroll
            for (int r = 0; r < 4; ++r) {
                const float p = exp2f(sB[t][r] * sclv[t]);
                lB[r] += p;
                PwB[(quad * 4 + r) * 68 + t * 16 + l16] = (unsigned short)(f_as_u(p) >> 16);
            }
        __builtin_amdgcn_s_waitcnt(0xC07F);

        {
            const short8 paA0 = *(const short8*)&PwA[l16 * 68 + quad * 8];
            const short8 paA1 = *(const short8*)&PwA[l16 * 68 + 32 + quad * 8];
            const short8 paB0 = *(const short8*)&PwB[l16 * 68 + quad * 8];
            const short8 paB1 = *(const short8*)&PwB[l16 * 68 + 32 + quad * 8];
            #pragma unroll
            for (int n = 0; n < 4; ++n) {
                oA[n] = MFMA16(paA0, vbf[n][0], oA[n]);
                oA[n] = MFMA16(paA1, vbf[n][1], oA[n]);
                oB[n] = MFMA16(paB0, vbf[n][0], oB[n]);
                oB[n] = MFMA16(paB1, vbf[n][1], oB[n]);
            }
        }
    }

    #pragma unroll
    for (int d = 1; d < 16; d <<= 1)
        #pragma unroll
        for (int r = 0; r < 4; r++) {
            lA[r] += __shfl_xor(lA[r], d, 16);
            lB[r] += __shfl_xor(lB[r], d, 16);
        }
    #pragma unroll
    for (int r = 0; r < 4; r++) { lA[r] = 1.0f / lA[r]; lB[r] = 1.0f / lB[r]; }
    #pragma unroll
    for (int n = 0; n < 4; n++)
        #pragma unroll
        for (int r = 0; r < 4; r++) {
            const int row = qt * 128 + wave * 16 + quad * 4 + r;
            out[(size_t)(b * 2048 + row) * 1024 + h * 64 + n * 16 + l16] = f2b(oA[n][r] * lA[r]);
            out[(size_t)(b * 2048 + row + 64) * 1024 + h * 64 + n * 16 + l16] = f2b(oB[n][r] * lB[r]);
        }
}
#endif

// ---------------------------------------------------------------------------
extern "C" void kernel_launch(void* const* d_in, const int* in_sizes, int n_in,
                              void* d_out, int out_size, void* d_ws, size_t ws_size,
                              hipStream_t stream) {
    const void* x  = d_in[0];
    const int*  mk = (const int*)d_in[1];
    const void* Wq = d_in[2]; const void* bq = d_in[3];
    const void* Wk = d_in[4]; const void* bk = d_in[5];
    const void* Wv = d_in[6]; const void* bv = d_in[7];
    const void* Wo = d_in[8]; const void* bo = d_in[9];

    char* wsb = (char*)d_ws;
    int* flag = (int*)wsb;                                   // 64B header
    unsigned short* W0 = (unsigned short*)(wsb + 64);

    const size_t M1 = 1024u * 1024u;
    const size_t M4 = 4096u * 1024u;
    unsigned short* xb  = W0;                                // 4M elems (reused as abf)
    unsigned short* WT  = xb + M4;                           // 3M: Wq^T|Wk^T|Wv^T
    unsigned short* WoT = WT + 3 * M1;                       // 1M (contiguous after WT)
    unsigned short* b3  = WoT + M1;                          // 3072 (pad 4096)
    unsigned short* bob = b3 + 4096;                         // 1024
    unsigned short* qkv = bob + 1024;                        // 12M (V third unused)
    unsigned short* VtG = qkv + (size_t)4096 * 3072;         // 4M  (total ~48MB)
    unsigned short* abf = xb;                                // alias: x dead after QKV GEMM

    detect_dtype<<<1, 256, 0, stream>>>((const unsigned short*)x, flag);

    convert_x<<<(4194304 + 255) / 256, 256, 0, stream>>>(x, xb, 4194304, flag);
    convtrans_k<<<dim3(16, 16, 5), 256, 0, stream>>>(Wq, Wk, Wv, Wo, bq, bk, bv, bo,
                                                     WT, b3, bob, flag);

    gemm_bias_relu<<<dim3(24, 32), 256, 0, stream>>>(xb, x, WT, b3, qkv, VtG, flag, 4096, 3072, 1024, 2);
    attn_kernel<<<dim3(16, 32), 256, 0, stream>>>(qkv, VtG, mk, abf);
    gemm_bias_relu<<<dim3(8, 32), 256, 0, stream>>>(abf, nullptr, WoT, bob, d_out, VtG, flag, 4096, 1024, 1024, 1);
}

// Round 11
// 237.846 us; speedup vs baseline: 1.2078x; 1.0235x over previous
//
#include <hip/hip_runtime.h>
#include <stdint.h>

typedef __attribute__((ext_vector_type(8))) short short8;   // 8 bf16 (4 VGPRs)
typedef __attribute__((ext_vector_type(4))) short short4b;  // 4 bf16 (2 VGPRs)
typedef __attribute__((ext_vector_type(4))) float f32x4;    // MFMA acc
typedef __attribute__((ext_vector_type(4))) unsigned short ushort4_t;

#define MFMA16(a, b, c) __builtin_amdgcn_mfma_f32_16x16x32_bf16((a), (b), (c), 0, 0, 0)

// 16x16x16 bf16 MFMA: device pass has the _1k builtin on gfx950 (proven in
// round 9 — v2 kernel ran). Host pass lacks it -> parse-only stub (host never
// executes device code).
#if defined(__HIP_DEVICE_COMPILE__)
  #if __has_builtin(__builtin_amdgcn_mfma_f32_16x16x16bf16_1k)
    #define MFMA16K16(a, b, c) __builtin_amdgcn_mfma_f32_16x16x16bf16_1k((a), (b), (c), 0, 0, 0)
  #else
    #define MFMA16K16(a, b, c) __builtin_amdgcn_mfma_f32_16x16x16_bf16((a), (b), (c), 0, 0, 0)
  #endif
#else
  #define MFMA16K16(a, b, c) (c)
#endif

__device__ __forceinline__ float b2f(unsigned short u) {
    union { unsigned u; float f; } c; c.u = ((unsigned)u) << 16; return c.f;
}
__device__ __forceinline__ unsigned short f2b(float f) {
    union { float f; unsigned u; } c; c.f = f;
    unsigned r = c.u + 0x7FFF + ((c.u >> 16) & 1);   // round-to-nearest-even
    return (unsigned short)(r >> 16);
}
__device__ __forceinline__ unsigned f_as_u(float f) {
    union { float f; unsigned u; } c; c.f = f; return c.u;
}

// async global->LDS, 16B per lane; LDS dest = wave-uniform base + lane*16.
__device__ __forceinline__ void g2lds16(const unsigned short* g, unsigned lds_byte_off) {
    __builtin_amdgcn_global_load_lds(
        (const __attribute__((address_space(1))) void*)(uintptr_t)g,
        (__attribute__((address_space(3))) void*)(uintptr_t)lds_byte_off,
        16, 0, 0);
}

// ---------------------------------------------------------------------------
// Dtype canary (proven): flag=1 => f32 inputs, 0 => bf16.
// ---------------------------------------------------------------------------
__global__ void detect_dtype(const unsigned short* __restrict__ x, int* __restrict__ flag) {
    __shared__ int cnt;
    if (threadIdx.x == 0) cnt = 0;
    __syncthreads();
    int insane = 0;
    #pragma unroll
    for (int j = 0; j < 4; ++j) {
        unsigned short u = x[threadIdx.x * 4 + j];
        int e = (u >> 7) & 0xFF;
        if ((e >= 1 && e <= 90) || e >= 165) insane++;
    }
    atomicAdd(&cnt, insane);
    __syncthreads();
    if (threadIdx.x == 0) *flag = (cnt > 128) ? 1 : 0;
}

// ---------------------------------------------------------------------------
// Fused convert+transpose for 4 weights (z=0..3), biases (z=4), and the
// x f32->bf16 conversion (z=5..12; early-exit when inputs already bf16).
// ---------------------------------------------------------------------------
__global__ __launch_bounds__(256) void convtrans_k(const void* __restrict__ s0, const void* __restrict__ s1,
                                                   const void* __restrict__ s2, const void* __restrict__ s3,
                                                   const void* __restrict__ b0, const void* __restrict__ b1,
                                                   const void* __restrict__ b2, const void* __restrict__ b3s,
                                                   const void* __restrict__ xsrc,
                                                   unsigned short* __restrict__ xdst,
                                                   unsigned short* __restrict__ dstBase,
                                                   unsigned short* __restrict__ dstB3,
                                                   unsigned short* __restrict__ dstBo,
                                                   const int* __restrict__ flag) {
    const int z = blockIdx.z;
    if (z >= 5) {           // x conversion: 8 slices x 256 blocks x 256 thr x 8 elems
        if (!*flag) return;
        const int slice = z - 5;
        const size_t i0 = (size_t)slice * 524288 + (blockIdx.y * 16 + blockIdx.x) * 2048 + threadIdx.x * 8;
        const float* s = (const float*)xsrc;
        float4 f0 = *(const float4*)&s[i0];
        float4 f1 = *(const float4*)&s[i0 + 4];
        unsigned short* t = &xdst[i0];
        t[0] = f2b(f0.x); t[1] = f2b(f0.y); t[2] = f2b(f0.z); t[3] = f2b(f0.w);
        t[4] = f2b(f1.x); t[5] = f2b(f1.y); t[6] = f2b(f1.z); t[7] = f2b(f1.w);
        return;
    }
    if (z == 4) {           // biases
        if (blockIdx.y != 0 || blockIdx.x >= 4) return;
        const int w = blockIdx.x;
        const void* src = (w == 0) ? b0 : (w == 1) ? b1 : (w == 2) ? b2 : b3s;
        #pragma unroll
        for (int j = 0; j < 4; ++j) {
            const int i = threadIdx.x * 4 + j;
            unsigned short v = (*flag) ? f2b(((const float*)src)[i]) : ((const unsigned short*)src)[i];
            if (w < 3) dstB3[w * 1024 + i] = v;
            else dstBo[i] = v;
        }
        return;
    }
    __shared__ __align__(16) unsigned short tile[64 * 72];
    const void* src = (z == 0) ? s0 : (z == 1) ? s1 : (z == 2) ? s2 : s3;
    unsigned short* dst = dstBase + (size_t)z * 1024 * 1024;
    const int tid = threadIdx.x;
    const int r0 = blockIdx.y * 64, c0 = blockIdx.x * 64;
    const int rb = tid >> 3, c = (tid & 7) * 8;
    if (*flag) {
        const float* s = (const float*)src;
        #pragma unroll
        for (int it = 0; it < 2; ++it) {
            int rr = it * 32 + rb;
            float4 f0 = *(const float4*)&s[(size_t)(r0 + rr) * 1024 + c0 + c];
            float4 f1 = *(const float4*)&s[(size_t)(r0 + rr) * 1024 + c0 + c + 4];
            unsigned short* t = &tile[rr * 72 + c];
            t[0] = f2b(f0.x); t[1] = f2b(f0.y); t[2] = f2b(f0.z); t[3] = f2b(f0.w);
            t[4] = f2b(f1.x); t[5] = f2b(f1.y); t[6] = f2b(f1.z); t[7] = f2b(f1.w);
        }
    } else {
        const unsigned short* s = (const unsigned short*)src;
        #pragma unroll
        for (int it = 0; it < 2; ++it) {
            int rr = it * 32 + rb;
            *(short8*)&tile[rr * 72 + c] = *(const short8*)&s[(size_t)(r0 + rr) * 1024 + c0 + c];
        }
    }
    __syncthreads();
    #pragma unroll
    for (int it = 0; it < 2; ++it) {
        int n = it * 32 + rb, k8 = c;
        union { short8 s; unsigned short u[8]; } tmp;
        #pragma unroll
        for (int j = 0; j < 8; ++j) tmp.u[j] = tile[(k8 + j) * 72 + n];
        *(short8*)&dst[(size_t)(c0 + n) * 1024 + r0 + k8] = tmp.s;
    }
}

// ---------------------------------------------------------------------------
// C = relu(A[M,K] @ BT[N,K]^T + bias[N]); m97 staging.
// mode 0: bf16. mode 1: final (f32/bf16 per flag). mode 2: QKV w/ V transposed.
// ---------------------------------------------------------------------------
__global__ __launch_bounds__(256) void gemm_bias_relu(const unsigned short* __restrict__ A,
                                                      const void* __restrict__ Araw,
                                                      const unsigned short* __restrict__ BT,
                                                      const unsigned short* __restrict__ bias,
                                                      void* __restrict__ C,
                                                      unsigned short* __restrict__ VtG,
                                                      const int* __restrict__ flag,
                                                      int M, int N, int K, int mode) {
    __shared__ __align__(16) unsigned short As[128 * 32];
    __shared__ __align__(16) unsigned short Bs[128 * 32];
    const int tid = threadIdx.x;
    const int wave = tid >> 6, lane = tid & 63;
    const int quad = lane >> 4, l16 = lane & 15;
    const int wm = wave >> 1, wn = wave & 1;
    const int m0 = blockIdx.y * 128, n0 = blockIdx.x * 128;

    const unsigned short* Ause = (Araw != nullptr && *flag == 0) ? (const unsigned short*)Araw : A;

    f32x4 acc[4][4];
    #pragma unroll
    for (int i = 0; i < 4; i++)
        #pragma unroll
        for (int j = 0; j < 4; j++) acc[i][j] = (f32x4){0.f, 0.f, 0.f, 0.f};

    const int srow = wave * 32 + (lane >> 2);
    const int sc8  = (lane & 3) * 8;
    const unsigned short* gA0 = Ause + (size_t)(m0 + srow) * K + sc8;
    const unsigned short* gA1 = gA0 + (size_t)16 * K;
    const unsigned short* gB0 = BT + (size_t)(n0 + srow) * K + sc8;
    const unsigned short* gB1 = gB0 + (size_t)16 * K;
    const unsigned ldsA = (unsigned)(uintptr_t)&As[0] + wave * 2048;
    const unsigned ldsB = (unsigned)(uintptr_t)&Bs[0] + wave * 2048;

    for (int k0 = 0; k0 < K; k0 += 32) {
        __syncthreads();
        g2lds16(gA0 + k0, ldsA);
        g2lds16(gA1 + k0, ldsA + 1024);
        g2lds16(gB0 + k0, ldsB);
        g2lds16(gB1 + k0, ldsB + 1024);
        __syncthreads();
        short8 af[4], bf[4];
        #pragma unroll
        for (int i = 0; i < 4; i++) af[i] = *(const short8*)&As[(wm * 64 + i * 16 + l16) * 32 + quad * 8];
        #pragma unroll
        for (int j = 0; j < 4; j++) bf[j] = *(const short8*)&Bs[(wn * 64 + j * 16 + l16) * 32 + quad * 8];
        #pragma unroll
        for (int i = 0; i < 4; i++)
            #pragma unroll
            for (int j = 0; j < 4; j++)
                acc[i][j] = MFMA16(af[i], bf[j], acc[i][j]);
    }

    if (mode == 2 && n0 >= 2048) {
        #pragma unroll
        for (int j = 0; j < 4; j++) {
            const int col = n0 + wn * 64 + j * 16 + l16;
            const int h  = (col - 2048) >> 6;
            const int dk = (col - 2048) & 63;
            const float bj = b2f(bias[col]);
            #pragma unroll
            for (int i = 0; i < 4; i++) {
                const int rowb = m0 + wm * 64 + i * 16 + quad * 4;
                const int bb = rowb >> 11;
                const int s0 = rowb & 2047;
                ushort4_t w;
                #pragma unroll
                for (int r = 0; r < 4; r++) {
                    float v = acc[i][j][r] + bj;
                    v = v > 0.f ? v : 0.f;
                    w[r] = f2b(v);
                }
                *(ushort4_t*)&VtG[(size_t)((bb * 16 + h) * 64 + dk) * 2048 + s0] = w;
            }
        }
    } else {
        const int f32out = (mode == 1) && (*flag != 0);
        #pragma unroll
        for (int j = 0; j < 4; j++) {
            const int col = n0 + wn * 64 + j * 16 + l16;
            const float bj = b2f(bias[col]);
            #pragma unroll
            for (int i = 0; i < 4; i++) {
                const int rowb = m0 + wm * 64 + i * 16 + quad * 4;
                #pragma unroll
                for (int r = 0; r < 4; r++) {
                    float v = acc[i][j][r] + bj;
                    v = v > 0.f ? v : 0.f;
                    if (f32out) ((float*)C)[(size_t)(rowb + r) * N + col] = v;
                    else ((unsigned short*)C)[(size_t)(rowb + r) * N + col] = f2b(v);
                }
            }
        }
    }
}

// ---------------------------------------------------------------------------
// Attention v3: S^T trick (round 9) + ones-column MFMA denominator + perm
// pack. l-sum via 8 extra K=16 MFMAs (B = all-ones) instead of 32 VALU adds;
// denominator lands in C-layout rows matching O (no shuffles; numerator and
// denominator use identical truncated-bf16 P). Pack via v_perm.
// ---------------------------------------------------------------------------
__global__ __launch_bounds__(256) void attn_kernel(const unsigned short* __restrict__ qkv,
                                                   const unsigned short* __restrict__ VtG,
                                                   const int* __restrict__ mask,
                                                   unsigned short* __restrict__ out) {
    __shared__ __align__(16) unsigned short Ks[64 * 72];    // [key][dk]
    __shared__ __align__(16) unsigned short Vs[64 * 72];    // [dk][key]
    __shared__ __align__(16) float maskF[2048];             // 0 (masked) or SCL

    const int qt = blockIdx.x, bh = blockIdx.y;
    const int b = bh >> 4, h = bh & 15;
    const int tid = threadIdx.x, wave = tid >> 6, lane = tid & 63;
    const int quad = lane >> 4, l16 = lane & 15;

    const float SCL = 0.125f * 1.44269504f;   // dk^-0.5 folded with log2(e)
    for (int i = tid; i < 2048; i += 256) maskF[i] = mask[b * 2048 + i] ? 0.f : SCL;

    const int qrowA = qt * 128 + wave * 16 + l16;
    const unsigned short* qpA = qkv + (size_t)(b * 2048 + qrowA) * 3072 + h * 64;
    const unsigned short* qpB = qpA + (size_t)64 * 3072;
    const short8 qa0 = *(const short8*)(qpA + quad * 8);
    const short8 qa1 = *(const short8*)(qpA + 32 + quad * 8);
    const short8 qb0 = *(const short8*)(qpB + quad * 8);
    const short8 qb1 = *(const short8*)(qpB + 32 + quad * 8);

    f32x4 oA[4], oB[4], sumA, sumB;
    #pragma unroll
    for (int n = 0; n < 4; n++) { oA[n] = (f32x4){0.f,0.f,0.f,0.f}; oB[n] = (f32x4){0.f,0.f,0.f,0.f}; }
    sumA = (f32x4){0.f,0.f,0.f,0.f};
    sumB = (f32x4){0.f,0.f,0.f,0.f};

    const short4b ones = { (short)0x3F80, (short)0x3F80, (short)0x3F80, (short)0x3F80 };  // bf16 1.0

    const int srow = tid >> 2;          // 0..63
    const int scol = (tid & 3) * 16;    // 0,16,32,48
    const unsigned short* kg = qkv + (size_t)(b * 2048 + srow) * 3072 + 1024 + h * 64 + scol;
    const unsigned short* vg = VtG + (size_t)(bh * 64 + srow) * 2048 + scol;
    const size_t kstep = (size_t)64 * 3072;
    unsigned short* wK = &Ks[srow * 72 + scol];
    unsigned short* wV = &Vs[srow * 72 + scol];

    for (int kt = 0; kt < 32; ++kt) {
        __syncthreads();
        *(short8*)wK       = *(const short8*)(kg + kt * kstep);
        *(short8*)(wK + 8) = *(const short8*)(kg + kt * kstep + 8);
        *(short8*)wV       = *(const short8*)(vg + kt * 64);
        *(short8*)(wV + 8) = *(const short8*)(vg + kt * 64 + 8);
        __syncthreads();

        // S^T per 16-key subtile: acc[r] = S[q=l16][key=t*16+quad*4+r]
        f32x4 sA[4], sB[4];
        #pragma unroll
        for (int t = 0; t < 4; ++t) {
            const short8 kb0 = *(const short8*)&Ks[(t * 16 + l16) * 72 + quad * 8];
            const short8 kb1 = *(const short8*)&Ks[(t * 16 + l16) * 72 + 32 + quad * 8];
            f32x4 z = (f32x4){0.f, 0.f, 0.f, 0.f};
            sA[t] = MFMA16(kb1, qa1, MFMA16(kb0, qa0, z));
            sB[t] = MFMA16(kb1, qb1, MFMA16(kb0, qb0, z));
        }

        // V B-frags (16x16x16): B[k=t*16+quad*4+j][n=dkblk*16+l16]
        short4b vb[4][4];
        #pragma unroll
        for (int t = 0; t < 4; ++t)
            #pragma unroll
            for (int n = 0; n < 4; ++n)
                vb[t][n] = *(const short4b*)&Vs[(n * 16 + l16) * 72 + t * 16 + quad * 4];

        #pragma unroll
        for (int t = 0; t < 4; ++t) {
            const f32x4 scl = *(const f32x4*)&maskF[kt * 64 + t * 16 + quad * 4];
            float pA[4], pB[4];
            #pragma unroll
            for (int r = 0; r < 4; ++r) {
                pA[r] = exp2f(sA[t][r] * scl[r]);
                pB[r] = exp2f(sB[t][r] * scl[r]);
            }
            // truncating pack via v_perm: selects bytes {3,2} of each src pair
            union { unsigned u[2]; short4b s; } fa, fb;
            fa.u[0] = __builtin_amdgcn_perm(f_as_u(pA[1]), f_as_u(pA[0]), 0x07060302u);
            fa.u[1] = __builtin_amdgcn_perm(f_as_u(pA[3]), f_as_u(pA[2]), 0x07060302u);
            fb.u[0] = __builtin_amdgcn_perm(f_as_u(pB[1]), f_as_u(pB[0]), 0x07060302u);
            fb.u[1] = __builtin_amdgcn_perm(f_as_u(pB[3]), f_as_u(pB[2]), 0x07060302u);
            #pragma unroll
            for (int n = 0; n < 4; ++n) {
                oA[n] = MFMA16K16(fa.s, vb[t][n], oA[n]);
                oB[n] = MFMA16K16(fb.s, vb[t][n], oB[n]);
            }
            sumA = MFMA16K16(fa.s, ones, sumA);   // row-sum of P -> C-layout rows
            sumB = MFMA16K16(fb.s, ones, sumB);
        }
    }

    // sum[r] (C layout, row q=quad*4+r) is the full denominator for that row.
    float invA[4], invB[4];
    #pragma unroll
    for (int r = 0; r < 4; ++r) { invA[r] = 1.0f / sumA[r]; invB[r] = 1.0f / sumB[r]; }
    #pragma unroll
    for (int n = 0; n < 4; n++)
        #pragma unroll
        for (int r = 0; r < 4; r++) {
            const int row = qt * 128 + wave * 16 + quad * 4 + r;
            out[(size_t)(b * 2048 + row) * 1024 + h * 64 + n * 16 + l16] = f2b(oA[n][r] * invA[r]);
            out[(size_t)(b * 2048 + row + 64) * 1024 + h * 64 + n * 16 + l16] = f2b(oB[n][r] * invB[r]);
        }
}

// ---------------------------------------------------------------------------
extern "C" void kernel_launch(void* const* d_in, const int* in_sizes, int n_in,
                              void* d_out, int out_size, void* d_ws, size_t ws_size,
                              hipStream_t stream) {
    const void* x  = d_in[0];
    const int*  mk = (const int*)d_in[1];
    const void* Wq = d_in[2]; const void* bq = d_in[3];
    const void* Wk = d_in[4]; const void* bk = d_in[5];
    const void* Wv = d_in[6]; const void* bv = d_in[7];
    const void* Wo = d_in[8]; const void* bo = d_in[9];

    char* wsb = (char*)d_ws;
    int* flag = (int*)wsb;                                   // 64B header
    unsigned short* W0 = (unsigned short*)(wsb + 64);

    const size_t M1 = 1024u * 1024u;
    const size_t M4 = 4096u * 1024u;
    unsigned short* xb  = W0;                                // 4M elems (reused as abf)
    unsigned short* WT  = xb + M4;                           // 3M: Wq^T|Wk^T|Wv^T
    unsigned short* WoT = WT + 3 * M1;                       // 1M (contiguous after WT)
    unsigned short* b3  = WoT + M1;                          // 3072 (pad 4096)
    unsigned short* bob = b3 + 4096;                         // 1024
    unsigned short* qkv = bob + 1024;                        // 12M (V third unused)
    unsigned short* VtG = qkv + (size_t)4096 * 3072;         // 4M  (total ~48MB)
    unsigned short* abf = xb;                                // alias: x dead after QKV GEMM

    detect_dtype<<<1, 256, 0, stream>>>((const unsigned short*)x, flag);

    convtrans_k<<<dim3(16, 16, 13), 256, 0, stream>>>(Wq, Wk, Wv, Wo, bq, bk, bv, bo,
                                                      x, xb, WT, b3, bob, flag);

    gemm_bias_relu<<<dim3(24, 32), 256, 0, stream>>>(xb, x, WT, b3, qkv, VtG, flag, 4096, 3072, 1024, 2);
    attn_kernel<<<dim3(16, 32), 256, 0, stream>>>(qkv, VtG, mk, abf);
    gemm_bias_relu<<<dim3(8, 32), 256, 0, stream>>>(abf, nullptr, WoT, bob, d_out, VtG, flag, 4096, 1024, 1024, 1);
}